// Round 1
// baseline (693.651 us; speedup 1.0000x reference)
//
#include <hip/hip_runtime.h>
#include <math.h>

#define HID 128
#define INDIM 6

typedef float4 f4;

// ---------------- utility ----------------
__global__ void k_zero_i(int* p, int n) {
    int i = blockIdx.x * blockDim.x + threadIdx.x;
    if (i < n) p[i] = 0;
}

// ---------------- degree ----------------
__global__ void k_deg(const int* dst, int* deg, int E) {
    int e = blockIdx.x * blockDim.x + threadIdx.x;
    if (e < E) atomicAdd(&deg[dst[e]], 1);
}

// single-block exclusive scan of deg -> rowptr  (N up to 1024*chunk)
__global__ void k_scan(const int* deg, int* rowptr, int N) {
    __shared__ int part[1024];
    int t = threadIdx.x;
    int chunk = (N + 1023) >> 10;
    int b = t * chunk;
    int en = min(b + chunk, N);
    int s = 0;
    for (int i = b; i < en; i++) s += deg[i];
    part[t] = s;
    __syncthreads();
    for (int off = 1; off < 1024; off <<= 1) {
        int v = (t >= off) ? part[t - off] : 0;
        __syncthreads();
        part[t] += v;
        __syncthreads();
    }
    int run = (t == 0) ? 0 : part[t - 1];
    for (int i = b; i < en; i++) { rowptr[i] = run; run += deg[i]; }
    if (t == 1023) rowptr[N] = run;
}

__global__ void k_fill(const int* ei, int* cursor, const int* rowptr, int* csr, int E) {
    int e = blockIdx.x * blockDim.x + threadIdx.x;
    if (e < E) {
        int d = ei[E + e];                       // dst row
        int pos = rowptr[d] + atomicAdd(&cursor[d], 1);
        csr[pos] = ei[e];                        // src
    }
}

__global__ void k_invdeg(const int* deg, float* invd, int N) {
    int i = blockIdx.x * blockDim.x + threadIdx.x;
    if (i < N) invd[i] = 1.0f / (float)max(deg[i], 1);
}

// ---------------- layer 0 (fused agg + 6->128 x2 matmul) ----------------
__global__ void k_layer0(const float* __restrict__ x, const int* __restrict__ rowptr,
                         const int* __restrict__ csr, const float* __restrict__ invd,
                         const float* __restrict__ wl, const float* __restrict__ bl,
                         const float* __restrict__ wr, float* __restrict__ out, int N) {
    int w = threadIdx.x >> 6, lid = threadIdx.x & 63;
    int n = blockIdx.x * 4 + w;
    if (n >= N) return;
    int s = rowptr[n], e = rowptr[n + 1];
    float acc = 0.f;
    if (lid < INDIM) {
        for (int i = s; i < e; i++) acc += x[csr[i] * INDIM + lid];
    }
    float id = invd[n];
    float m[INDIM], xr[INDIM];
#pragma unroll
    for (int i = 0; i < INDIM; i++) {
        m[i]  = __shfl(acc, i, 64) * id;
        xr[i] = x[n * INDIM + i];
    }
#pragma unroll
    for (int rep = 0; rep < 2; rep++) {
        int o = lid + rep * 64;
        float h = bl[o];
#pragma unroll
        for (int i = 0; i < INDIM; i++)
            h = fmaf(m[i], wl[o * INDIM + i], fmaf(xr[i], wr[o * INDIM + i], h));
        out[n * HID + o] = h;
    }
}

// ---------------- batch norm ----------------
__global__ void k_bnstats(const float* __restrict__ h, float* sum, float* sq, int N) {
    int t = threadIdx.x;                // 128 threads, t == feature
    int n0 = blockIdx.x * 128;
    float s = 0.f, q = 0.f;
    for (int i = 0; i < 128; i++) {
        int n = n0 + i;
        if (n < N) {
            float v = h[n * HID + t];
            s += v; q += v * v;
        }
    }
    atomicAdd(&sum[t], s);
    atomicAdd(&sq[t], q);
}

__global__ void k_bnfin(const float* sum, const float* sq, const float* g, const float* b,
                        float* scale, float* shift, float invN) {
    int t = threadIdx.x;
    float mu  = sum[t] * invN;
    float var = sq[t] * invN - mu * mu;
    float sc  = g[t] * rsqrtf(var + 1e-5f);
    scale[t] = sc;
    shift[t] = b[t] - mu * sc;
}

__global__ void k_bnrelu(float* __restrict__ h, const float* __restrict__ scale,
                         const float* __restrict__ shift, int total4) {
    int i = blockIdx.x * blockDim.x + threadIdx.x;
    int stride = gridDim.x * blockDim.x;
    for (; i < total4; i += stride) {
        int f4i = i & 31;                 // 32 float4 per 128-feature row
        f4 v = ((const f4*)h)[i];
        f4 sc = ((const f4*)scale)[f4i];
        f4 sh = ((const f4*)shift)[f4i];
        f4 r;
        r.x = fmaxf(0.f, fmaf(v.x, sc.x, sh.x));
        r.y = fmaxf(0.f, fmaf(v.y, sc.y, sh.y));
        r.z = fmaxf(0.f, fmaf(v.z, sc.z, sh.z));
        r.w = fmaxf(0.f, fmaf(v.w, sc.w, sh.w));
        ((f4*)h)[i] = r;
    }
}

// ---------------- 128-dim mean aggregation (CSR gather, wave per node) ----------------
__global__ void k_agg(const float* __restrict__ h, const int* __restrict__ rowptr,
                      const int* __restrict__ csr, const float* __restrict__ invd,
                      float* __restrict__ out, int N) {
    int w = threadIdx.x >> 6, lid = threadIdx.x & 63;
    int n = blockIdx.x * 4 + w;
    if (n >= N) return;
    int s = rowptr[n], e = rowptr[n + 1];
    float2 acc = make_float2(0.f, 0.f);
    for (int i = s; i < e; i++) {
        int src = csr[i];
        float2 v = *(const float2*)&h[src * HID + lid * 2];
        acc.x += v.x; acc.y += v.y;
    }
    float id = invd[n];
    float2 r = make_float2(acc.x * id, acc.y * id);
    *(float2*)&out[n * HID + lid * 2] = r;
}

// ---------------- fused double GEMM: C = Bm@Wl^T + Ar@Wr^T + bias ----------------
__global__ __launch_bounds__(256) void k_gemm(
        const float* __restrict__ Bm, const float* __restrict__ Ar,
        const float* __restrict__ Wl, const float* __restrict__ Wr,
        const float* __restrict__ bias, float* __restrict__ C, int N) {
    __shared__ float As[32][132];
    __shared__ float Ws[32][132];
    int t = threadIdx.x;
    int row0 = blockIdx.x * 128;
    int tx = t & 15, ty = t >> 4;
    float acc[8][8];
#pragma unroll
    for (int i = 0; i < 8; i++)
#pragma unroll
        for (int j = 0; j < 8; j++) acc[i][j] = 0.f;

    for (int kk = 0; kk < 8; kk++) {
        const float* S = (kk < 4) ? Bm : Ar;
        const float* W = (kk < 4) ? Wl : Wr;
        int kbase = (kk & 3) * 32;
#pragma unroll
        for (int j = 0; j < 4; j++) {
            int fi = t + j * 256;
            int r = fi >> 3, c4 = fi & 7;
            f4 v = make_float4(0.f, 0.f, 0.f, 0.f);
            int row = row0 + r;
            if (row < N) v = *(const f4*)&S[row * HID + kbase + c4 * 4];
            As[c4 * 4 + 0][r] = v.x; As[c4 * 4 + 1][r] = v.y;
            As[c4 * 4 + 2][r] = v.z; As[c4 * 4 + 3][r] = v.w;
            f4 wv = *(const f4*)&W[r * HID + kbase + c4 * 4];   // r == output o
            Ws[c4 * 4 + 0][r] = wv.x; Ws[c4 * 4 + 1][r] = wv.y;
            Ws[c4 * 4 + 2][r] = wv.z; Ws[c4 * 4 + 3][r] = wv.w;
        }
        __syncthreads();
#pragma unroll
        for (int k = 0; k < 32; k++) {
            float a[8], wv[8];
            *(f4*)&a[0]  = *(const f4*)&As[k][ty * 8];
            *(f4*)&a[4]  = *(const f4*)&As[k][ty * 8 + 4];
            *(f4*)&wv[0] = *(const f4*)&Ws[k][tx * 8];
            *(f4*)&wv[4] = *(const f4*)&Ws[k][tx * 8 + 4];
#pragma unroll
            for (int i = 0; i < 8; i++)
#pragma unroll
                for (int j = 0; j < 8; j++)
                    acc[i][j] = fmaf(a[i], wv[j], acc[i][j]);
        }
        __syncthreads();
    }

    float bs[8];
#pragma unroll
    for (int j = 0; j < 8; j++) bs[j] = bias[tx * 8 + j];
#pragma unroll
    for (int i = 0; i < 8; i++) {
        int row = row0 + ty * 8 + i;
        if (row < N) {
            f4 r0 = make_float4(acc[i][0] + bs[0], acc[i][1] + bs[1],
                                acc[i][2] + bs[2], acc[i][3] + bs[3]);
            f4 r1 = make_float4(acc[i][4] + bs[4], acc[i][5] + bs[5],
                                acc[i][6] + bs[6], acc[i][7] + bs[7]);
            *(f4*)&C[row * HID + tx * 8]     = r0;
            *(f4*)&C[row * HID + tx * 8 + 4] = r1;
        }
    }
}

// ---------------- fused layer 2: agg + dual dot + sigmoid ----------------
__global__ void k_final(const float* __restrict__ h, const int* __restrict__ rowptr,
                        const int* __restrict__ csr, const float* __restrict__ invd,
                        const float* __restrict__ wl2, const float* __restrict__ bl2,
                        const float* __restrict__ wr2, float* __restrict__ out, int N) {
    int w = threadIdx.x >> 6, lid = threadIdx.x & 63;
    int n = blockIdx.x * 4 + w;
    if (n >= N) return;
    int s = rowptr[n], e = rowptr[n + 1];
    float2 acc = make_float2(0.f, 0.f);
    for (int i = s; i < e; i++) {
        int src = csr[i];
        float2 v = *(const float2*)&h[src * HID + lid * 2];
        acc.x += v.x; acc.y += v.y;
    }
    float id = invd[n];
    float2 root = *(const float2*)&h[n * HID + lid * 2];
    float2 wl = *(const float2*)&wl2[lid * 2];
    float2 wr = *(const float2*)&wr2[lid * 2];
    float p = acc.x * id * wl.x + acc.y * id * wl.y + root.x * wr.x + root.y * wr.y;
#pragma unroll
    for (int off = 32; off > 0; off >>= 1) p += __shfl_down(p, off, 64);
    if (lid == 0) out[n] = 1.f / (1.f + expf(-(p + bl2[0])));
}

// ---------------- host ----------------
extern "C" void kernel_launch(void* const* d_in, const int* in_sizes, int n_in,
                              void* d_out, int out_size, void* d_ws, size_t ws_size,
                              hipStream_t stream) {
    const float* x   = (const float*)d_in[0];
    const int*   ei  = (const int*)d_in[1];
    const float* wl0 = (const float*)d_in[2];
    const float* bl0 = (const float*)d_in[3];
    const float* wr0 = (const float*)d_in[4];
    const float* g0  = (const float*)d_in[5];
    const float* be0 = (const float*)d_in[6];
    const float* wl1 = (const float*)d_in[7];
    const float* bl1 = (const float*)d_in[8];
    const float* wr1 = (const float*)d_in[9];
    const float* g1  = (const float*)d_in[10];
    const float* be1 = (const float*)d_in[11];
    const float* wl2 = (const float*)d_in[12];
    const float* bl2 = (const float*)d_in[13];
    const float* wr2 = (const float*)d_in[14];
    float* outp = (float*)d_out;

    int N = in_sizes[0] / INDIM;     // 100000
    int E = in_sizes[1] / 2;         // 600000

    char* ws = (char*)d_ws;
    size_t off = 0;
    auto alloc = [&](size_t bytes) { size_t o = off; off = (off + bytes + 255) & ~(size_t)255; return o; };
    int*   degi   = (int*)(ws + alloc((size_t)N * 4));
    int*   cursor = (int*)(ws + alloc((size_t)N * 4));
    int*   rowptr = (int*)(ws + alloc((size_t)(N + 1) * 4));
    int*   csr    = (int*)(ws + alloc((size_t)E * 4));
    float* invd   = (float*)(ws + alloc((size_t)N * 4));
    float* bn     = (float*)(ws + alloc(1024 * 4));
    // bn layout: sum0[128] sq0[128] sum1[128] sq1[128] scale0[128] shift0[128] scale1[128] shift1[128]
    float* sum0 = bn, *sq0 = bn + 128, *sum1 = bn + 256, *sq1 = bn + 384;
    float* sc0 = bn + 512, *sh0 = bn + 640, *sc1 = bn + 768, *sh1 = bn + 896;
    float* bufA = (float*)(ws + alloc((size_t)N * HID * 4));
    float* bufB = (float*)(ws + alloc((size_t)N * HID * 4));

    float invN = 1.0f / (float)N;
    int gE = (E + 255) / 256;
    int gN = (N + 255) / 256;
    int gW = (N + 3) / 4;            // wave-per-node kernels
    int gS = (N + 127) / 128;        // bnstats / gemm blocks
    int total4 = N * (HID / 4);

    // zero accumulators
    k_zero_i<<<gN, 256, 0, stream>>>(degi, N);
    k_zero_i<<<gN, 256, 0, stream>>>(cursor, N);
    k_zero_i<<<(512 + 255) / 256, 256, 0, stream>>>((int*)bn, 512);

    // CSR build
    k_deg<<<gE, 256, 0, stream>>>(ei + E, degi, E);
    k_scan<<<1, 1024, 0, stream>>>(degi, rowptr, N);
    k_fill<<<gE, 256, 0, stream>>>(ei, cursor, rowptr, csr, E);
    k_invdeg<<<gN, 256, 0, stream>>>(degi, invd, N);

    // layer 0 -> bufA (pre-BN)
    k_layer0<<<gW, 256, 0, stream>>>(x, rowptr, csr, invd, wl0, bl0, wr0, bufA, N);
    k_bnstats<<<gS, 128, 0, stream>>>(bufA, sum0, sq0, N);
    k_bnfin<<<1, 128, 0, stream>>>(sum0, sq0, g0, be0, sc0, sh0, invN);
    k_bnrelu<<<2048, 256, 0, stream>>>(bufA, sc0, sh0, total4);

    // layer 1: agg(bufA)->bufB ; gemm -> bufB (in place)
    k_agg<<<gW, 256, 0, stream>>>(bufA, rowptr, csr, invd, bufB, N);
    k_gemm<<<gS, 256, 0, stream>>>(bufB, bufA, wl1, wr1, bl1, bufB, N);
    k_bnstats<<<gS, 128, 0, stream>>>(bufB, sum1, sq1, N);
    k_bnfin<<<1, 128, 0, stream>>>(sum1, sq1, g1, be1, sc1, sh1, invN);
    k_bnrelu<<<2048, 256, 0, stream>>>(bufB, sc1, sh1, total4);

    // layer 2 fused: agg + dot + sigmoid -> out
    k_final<<<gW, 256, 0, stream>>>(bufB, rowptr, csr, invd, wl2, bl2, wr2, outp, N);
}

// Round 2
// 548.065 us; speedup vs baseline: 1.2656x; 1.2656x over previous
//
#include <hip/hip_runtime.h>
#include <math.h>

#define HID 128
#define INDIM 6

typedef float4 f4;

// ---------------- utility ----------------
__global__ void k_zero_i(int* p, int n) {
    int i = blockIdx.x * blockDim.x + threadIdx.x;
    if (i < n) p[i] = 0;
}

// ---------------- degree ----------------
__global__ void k_deg(const int* dst, int* deg, int E) {
    int e = blockIdx.x * blockDim.x + threadIdx.x;
    if (e < E) atomicAdd(&deg[dst[e]], 1);
}

// ---------------- hierarchical exclusive scan (deg -> rowptr) ----------------
// pass 1: per-block (1024 elems) reduce -> partial[b]
__global__ void k_scan_partial(const int* __restrict__ deg, int* __restrict__ partial, int N) {
    __shared__ int lds[256];
    int t = threadIdx.x;
    int base = blockIdx.x * 1024 + t * 4;
    int s = 0;
    if (base + 4 <= N) {
        int4 v = *(const int4*)&deg[base];
        s = v.x + v.y + v.z + v.w;
    } else {
        for (int i = 0; i < 4; i++) if (base + i < N) s += deg[base + i];
    }
    lds[t] = s;
    __syncthreads();
    for (int off = 128; off > 0; off >>= 1) {
        if (t < off) lds[t] += lds[t + off];
        __syncthreads();
    }
    if (t == 0) partial[blockIdx.x] = lds[0];
}

// pass 2: single-block exclusive scan of partials in place (nb <= 1024)
__global__ void k_scan_tops(int* partial, int nb) {
    __shared__ int lds[1024];
    int t = threadIdx.x;
    lds[t] = (t < nb) ? partial[t] : 0;
    __syncthreads();
    for (int off = 1; off < 1024; off <<= 1) {
        int v = (t >= off) ? lds[t - off] : 0;
        __syncthreads();
        lds[t] += v;
        __syncthreads();
    }
    if (t < nb) partial[t] = (t == 0) ? 0 : lds[t - 1];
}

// pass 3: per-block local scan + block offset -> rowptr; rowptr[N] = E
__global__ void k_scan_write(const int* __restrict__ deg, const int* __restrict__ partial,
                             int* __restrict__ rowptr, int N, int E) {
    __shared__ int lds[256];
    int t = threadIdx.x;
    int base = blockIdx.x * 1024 + t * 4;
    int v0 = 0, v1 = 0, v2 = 0, v3 = 0;
    if (base + 4 <= N) {
        int4 v = *(const int4*)&deg[base];
        v0 = v.x; v1 = v.y; v2 = v.z; v3 = v.w;
    } else {
        if (base + 0 < N) v0 = deg[base + 0];
        if (base + 1 < N) v1 = deg[base + 1];
        if (base + 2 < N) v2 = deg[base + 2];
        if (base + 3 < N) v3 = deg[base + 3];
    }
    lds[t] = v0 + v1 + v2 + v3;
    __syncthreads();
    for (int off = 1; off < 256; off <<= 1) {
        int v = (t >= off) ? lds[t - off] : 0;
        __syncthreads();
        lds[t] += v;
        __syncthreads();
    }
    int run = partial[blockIdx.x] + ((t == 0) ? 0 : lds[t - 1]);
    if (base + 0 < N) rowptr[base + 0] = run; run += v0;
    if (base + 1 < N) rowptr[base + 1] = run; run += v1;
    if (base + 2 < N) rowptr[base + 2] = run; run += v2;
    if (base + 3 < N) rowptr[base + 3] = run; run += v3;
    if (blockIdx.x == 0 && t == 0) rowptr[N] = E;
}

__global__ void k_fill(const int* ei, int* cursor, const int* rowptr, int* csr, int E) {
    int e = blockIdx.x * blockDim.x + threadIdx.x;
    if (e < E) {
        int d = ei[E + e];                       // dst row
        int pos = rowptr[d] + atomicAdd(&cursor[d], 1);
        csr[pos] = ei[e];                        // src
    }
}

__global__ void k_invdeg(const int* deg, float* invd, int N) {
    int i = blockIdx.x * blockDim.x + threadIdx.x;
    if (i < N) invd[i] = 1.0f / (float)max(deg[i], 1);
}

// ---------------- layer 0 (fused agg + 6->128 x2 matmul) ----------------
__global__ void k_layer0(const float* __restrict__ x, const int* __restrict__ rowptr,
                         const int* __restrict__ csr, const float* __restrict__ invd,
                         const float* __restrict__ wl, const float* __restrict__ bl,
                         const float* __restrict__ wr, float* __restrict__ out, int N) {
    int w = threadIdx.x >> 6, lid = threadIdx.x & 63;
    int n = blockIdx.x * 4 + w;
    if (n >= N) return;
    int s = rowptr[n], e = rowptr[n + 1];
    float acc = 0.f;
    if (lid < INDIM) {
        for (int i = s; i < e; i++) acc += x[csr[i] * INDIM + lid];
    }
    float id = invd[n];
    float m[INDIM], xr[INDIM];
#pragma unroll
    for (int i = 0; i < INDIM; i++) {
        m[i]  = __shfl(acc, i, 64) * id;
        xr[i] = x[n * INDIM + i];
    }
#pragma unroll
    for (int rep = 0; rep < 2; rep++) {
        int o = lid + rep * 64;
        float h = bl[o];
#pragma unroll
        for (int i = 0; i < INDIM; i++)
            h = fmaf(m[i], wl[o * INDIM + i], fmaf(xr[i], wr[o * INDIM + i], h));
        out[n * HID + o] = h;
    }
}

// ---------------- batch norm ----------------
__global__ void k_bnstats(const float* __restrict__ h, float* sum, float* sq, int N) {
    int t = threadIdx.x;                // 128 threads, t == feature
    int n0 = blockIdx.x * 128;
    float s = 0.f, q = 0.f;
    for (int i = 0; i < 128; i++) {
        int n = n0 + i;
        if (n < N) {
            float v = h[n * HID + t];
            s += v; q += v * v;
        }
    }
    atomicAdd(&sum[t], s);
    atomicAdd(&sq[t], q);
}

__global__ void k_bnfin(const float* sum, const float* sq, const float* g, const float* b,
                        float* scale, float* shift, float invN) {
    int t = threadIdx.x;
    float mu  = sum[t] * invN;
    float var = sq[t] * invN - mu * mu;
    float sc  = g[t] * rsqrtf(var + 1e-5f);
    scale[t] = sc;
    shift[t] = b[t] - mu * sc;
}

__global__ void k_bnrelu(float* __restrict__ h, const float* __restrict__ scale,
                         const float* __restrict__ shift, int total4) {
    int i = blockIdx.x * blockDim.x + threadIdx.x;
    int stride = gridDim.x * blockDim.x;
    for (; i < total4; i += stride) {
        int f4i = i & 31;                 // 32 float4 per 128-feature row
        f4 v = ((const f4*)h)[i];
        f4 sc = ((const f4*)scale)[f4i];
        f4 sh = ((const f4*)shift)[f4i];
        f4 r;
        r.x = fmaxf(0.f, fmaf(v.x, sc.x, sh.x));
        r.y = fmaxf(0.f, fmaf(v.y, sc.y, sh.y));
        r.z = fmaxf(0.f, fmaf(v.z, sc.z, sh.z));
        r.w = fmaxf(0.f, fmaf(v.w, sc.w, sh.w));
        ((f4*)h)[i] = r;
    }
}

// ---------------- 128-dim mean aggregation (CSR gather, wave per node) ----------------
__global__ void k_agg(const float* __restrict__ h, const int* __restrict__ rowptr,
                      const int* __restrict__ csr, const float* __restrict__ invd,
                      float* __restrict__ out, int N) {
    int w = threadIdx.x >> 6, lid = threadIdx.x & 63;
    int n = blockIdx.x * 4 + w;
    if (n >= N) return;
    int s = rowptr[n], e = rowptr[n + 1];
    float2 acc = make_float2(0.f, 0.f);
    for (int i = s; i < e; i++) {
        int src = csr[i];
        float2 v = *(const float2*)&h[src * HID + lid * 2];
        acc.x += v.x; acc.y += v.y;
    }
    float id = invd[n];
    float2 r = make_float2(acc.x * id, acc.y * id);
    *(float2*)&out[n * HID + lid * 2] = r;
}

// ---------------- fused double GEMM: C = Bm@Wl^T + Ar@Wr^T + bias ----------------
__global__ __launch_bounds__(256) void k_gemm(
        const float* __restrict__ Bm, const float* __restrict__ Ar,
        const float* __restrict__ Wl, const float* __restrict__ Wr,
        const float* __restrict__ bias, float* __restrict__ C, int N) {
    __shared__ float As[32][132];
    __shared__ float Ws[32][132];
    int t = threadIdx.x;
    int row0 = blockIdx.x * 128;
    int tx = t & 15, ty = t >> 4;
    float acc[8][8];
#pragma unroll
    for (int i = 0; i < 8; i++)
#pragma unroll
        for (int j = 0; j < 8; j++) acc[i][j] = 0.f;

    for (int kk = 0; kk < 8; kk++) {
        const float* S = (kk < 4) ? Bm : Ar;
        const float* W = (kk < 4) ? Wl : Wr;
        int kbase = (kk & 3) * 32;
#pragma unroll
        for (int j = 0; j < 4; j++) {
            int fi = t + j * 256;
            int r = fi >> 3, c4 = fi & 7;
            f4 v = make_float4(0.f, 0.f, 0.f, 0.f);
            int row = row0 + r;
            if (row < N) v = *(const f4*)&S[row * HID + kbase + c4 * 4];
            As[c4 * 4 + 0][r] = v.x; As[c4 * 4 + 1][r] = v.y;
            As[c4 * 4 + 2][r] = v.z; As[c4 * 4 + 3][r] = v.w;
            f4 wv = *(const f4*)&W[r * HID + kbase + c4 * 4];   // r == output o
            Ws[c4 * 4 + 0][r] = wv.x; Ws[c4 * 4 + 1][r] = wv.y;
            Ws[c4 * 4 + 2][r] = wv.z; Ws[c4 * 4 + 3][r] = wv.w;
        }
        __syncthreads();
#pragma unroll
        for (int k = 0; k < 32; k++) {
            float a[8], wv[8];
            *(f4*)&a[0]  = *(const f4*)&As[k][ty * 8];
            *(f4*)&a[4]  = *(const f4*)&As[k][ty * 8 + 4];
            *(f4*)&wv[0] = *(const f4*)&Ws[k][tx * 8];
            *(f4*)&wv[4] = *(const f4*)&Ws[k][tx * 8 + 4];
#pragma unroll
            for (int i = 0; i < 8; i++)
#pragma unroll
                for (int j = 0; j < 8; j++)
                    acc[i][j] = fmaf(a[i], wv[j], acc[i][j]);
        }
        __syncthreads();
    }

    float bs[8];
#pragma unroll
    for (int j = 0; j < 8; j++) bs[j] = bias[tx * 8 + j];
#pragma unroll
    for (int i = 0; i < 8; i++) {
        int row = row0 + ty * 8 + i;
        if (row < N) {
            f4 r0 = make_float4(acc[i][0] + bs[0], acc[i][1] + bs[1],
                                acc[i][2] + bs[2], acc[i][3] + bs[3]);
            f4 r1 = make_float4(acc[i][4] + bs[4], acc[i][5] + bs[5],
                                acc[i][6] + bs[6], acc[i][7] + bs[7]);
            *(f4*)&C[row * HID + tx * 8]     = r0;
            *(f4*)&C[row * HID + tx * 8 + 4] = r1;
        }
    }
}

// ---------------- fused layer 2: agg + dual dot + sigmoid ----------------
__global__ void k_final(const float* __restrict__ h, const int* __restrict__ rowptr,
                        const int* __restrict__ csr, const float* __restrict__ invd,
                        const float* __restrict__ wl2, const float* __restrict__ bl2,
                        const float* __restrict__ wr2, float* __restrict__ out, int N) {
    int w = threadIdx.x >> 6, lid = threadIdx.x & 63;
    int n = blockIdx.x * 4 + w;
    if (n >= N) return;
    int s = rowptr[n], e = rowptr[n + 1];
    float2 acc = make_float2(0.f, 0.f);
    for (int i = s; i < e; i++) {
        int src = csr[i];
        float2 v = *(const float2*)&h[src * HID + lid * 2];
        acc.x += v.x; acc.y += v.y;
    }
    float id = invd[n];
    float2 root = *(const float2*)&h[n * HID + lid * 2];
    float2 wl = *(const float2*)&wl2[lid * 2];
    float2 wr = *(const float2*)&wr2[lid * 2];
    float p = acc.x * id * wl.x + acc.y * id * wl.y + root.x * wr.x + root.y * wr.y;
#pragma unroll
    for (int off = 32; off > 0; off >>= 1) p += __shfl_down(p, off, 64);
    if (lid == 0) out[n] = 1.f / (1.f + expf(-(p + bl2[0])));
}

// ---------------- host ----------------
extern "C" void kernel_launch(void* const* d_in, const int* in_sizes, int n_in,
                              void* d_out, int out_size, void* d_ws, size_t ws_size,
                              hipStream_t stream) {
    const float* x   = (const float*)d_in[0];
    const int*   ei  = (const int*)d_in[1];
    const float* wl0 = (const float*)d_in[2];
    const float* bl0 = (const float*)d_in[3];
    const float* wr0 = (const float*)d_in[4];
    const float* g0  = (const float*)d_in[5];
    const float* be0 = (const float*)d_in[6];
    const float* wl1 = (const float*)d_in[7];
    const float* bl1 = (const float*)d_in[8];
    const float* wr1 = (const float*)d_in[9];
    const float* g1  = (const float*)d_in[10];
    const float* be1 = (const float*)d_in[11];
    const float* wl2 = (const float*)d_in[12];
    const float* bl2 = (const float*)d_in[13];
    const float* wr2 = (const float*)d_in[14];
    float* outp = (float*)d_out;

    int N = in_sizes[0] / INDIM;     // 100000
    int E = in_sizes[1] / 2;         // 600000

    char* ws = (char*)d_ws;
    size_t off = 0;
    auto alloc = [&](size_t bytes) { size_t o = off; off = (off + bytes + 255) & ~(size_t)255; return o; };
    int*   degi   = (int*)(ws + alloc((size_t)N * 4));
    int*   cursor = (int*)(ws + alloc((size_t)N * 4));
    int*   rowptr = (int*)(ws + alloc((size_t)(N + 1) * 4));
    int*   csr    = (int*)(ws + alloc((size_t)E * 4));
    float* invd   = (float*)(ws + alloc((size_t)N * 4));
    int*   partial= (int*)(ws + alloc(1024 * 4));
    float* bn     = (float*)(ws + alloc(1024 * 4));
    // bn layout: sum0[128] sq0[128] sum1[128] sq1[128] scale0[128] shift0[128] scale1[128] shift1[128]
    float* sum0 = bn, *sq0 = bn + 128, *sum1 = bn + 256, *sq1 = bn + 384;
    float* sc0 = bn + 512, *sh0 = bn + 640, *sc1 = bn + 768, *sh1 = bn + 896;
    float* bufA = (float*)(ws + alloc((size_t)N * HID * 4));
    float* bufB = (float*)(ws + alloc((size_t)N * HID * 4));

    float invN = 1.0f / (float)N;
    int gE = (E + 255) / 256;
    int gN = (N + 255) / 256;
    int gW = (N + 3) / 4;            // wave-per-node kernels
    int gS = (N + 127) / 128;        // bnstats / gemm blocks
    int nbScan = (N + 1023) / 1024;  // scan blocks (1024 elems per block)
    int total4 = N * (HID / 4);

    // zero accumulators
    k_zero_i<<<gN, 256, 0, stream>>>(degi, N);
    k_zero_i<<<gN, 256, 0, stream>>>(cursor, N);
    k_zero_i<<<(512 + 255) / 256, 256, 0, stream>>>((int*)bn, 512);

    // CSR build
    k_deg<<<gE, 256, 0, stream>>>(ei + E, degi, E);
    k_scan_partial<<<nbScan, 256, 0, stream>>>(degi, partial, N);
    k_scan_tops<<<1, 1024, 0, stream>>>(partial, nbScan);
    k_scan_write<<<nbScan, 256, 0, stream>>>(degi, partial, rowptr, N, E);
    k_fill<<<gE, 256, 0, stream>>>(ei, cursor, rowptr, csr, E);
    k_invdeg<<<gN, 256, 0, stream>>>(degi, invd, N);

    // layer 0 -> bufA (pre-BN)
    k_layer0<<<gW, 256, 0, stream>>>(x, rowptr, csr, invd, wl0, bl0, wr0, bufA, N);
    k_bnstats<<<gS, 128, 0, stream>>>(bufA, sum0, sq0, N);
    k_bnfin<<<1, 128, 0, stream>>>(sum0, sq0, g0, be0, sc0, sh0, invN);
    k_bnrelu<<<2048, 256, 0, stream>>>(bufA, sc0, sh0, total4);

    // layer 1: agg(bufA)->bufB ; gemm -> bufB (in place)
    k_agg<<<gW, 256, 0, stream>>>(bufA, rowptr, csr, invd, bufB, N);
    k_gemm<<<gS, 256, 0, stream>>>(bufB, bufA, wl1, wr1, bl1, bufB, N);
    k_bnstats<<<gS, 128, 0, stream>>>(bufB, sum1, sq1, N);
    k_bnfin<<<1, 128, 0, stream>>>(sum1, sq1, g1, be1, sc1, sh1, invN);
    k_bnrelu<<<2048, 256, 0, stream>>>(bufB, sc1, sh1, total4);

    // layer 2 fused: agg + dot + sigmoid -> out
    k_final<<<gW, 256, 0, stream>>>(bufB, rowptr, csr, invd, wl2, bl2, wr2, outp, N);
}

// Round 5
// 463.356 us; speedup vs baseline: 1.4970x; 1.1828x over previous
//
#include <hip/hip_runtime.h>
#include <math.h>

#define HID 128
#define INDIM 6

typedef float4 f4;
typedef __attribute__((ext_vector_type(8))) short short8;
typedef __attribute__((ext_vector_type(4))) float f32x4;

static __device__ inline unsigned short f2bf(float f) {
    union { float f; unsigned int u; } v; v.f = f;
    unsigned int r = v.u + 0x7fffu + ((v.u >> 16) & 1u);   // RNE
    return (unsigned short)(r >> 16);
}

// ---------------- utility ----------------
__global__ void k_zero_i(int* p, int n) {
    int i = blockIdx.x * blockDim.x + threadIdx.x;
    if (i < n) p[i] = 0;
}

// ---------------- degree ----------------
__global__ void k_deg(const int* dst, int* deg, int E) {
    int e = blockIdx.x * blockDim.x + threadIdx.x;
    if (e < E) atomicAdd(&deg[dst[e]], 1);
}

// ---------------- hierarchical exclusive scan (deg -> rowptr) ----------------
__global__ void k_scan_partial(const int* __restrict__ deg, int* __restrict__ partial, int N) {
    __shared__ int lds[256];
    int t = threadIdx.x;
    int base = blockIdx.x * 1024 + t * 4;
    int s = 0;
    if (base + 4 <= N) {
        int4 v = *(const int4*)&deg[base];
        s = v.x + v.y + v.z + v.w;
    } else {
        for (int i = 0; i < 4; i++) if (base + i < N) s += deg[base + i];
    }
    lds[t] = s;
    __syncthreads();
    for (int off = 128; off > 0; off >>= 1) {
        if (t < off) lds[t] += lds[t + off];
        __syncthreads();
    }
    if (t == 0) partial[blockIdx.x] = lds[0];
}

__global__ void k_scan_tops(int* partial, int nb) {
    __shared__ int lds[1024];
    int t = threadIdx.x;
    lds[t] = (t < nb) ? partial[t] : 0;
    __syncthreads();
    for (int off = 1; off < 1024; off <<= 1) {
        int v = (t >= off) ? lds[t - off] : 0;
        __syncthreads();
        lds[t] += v;
        __syncthreads();
    }
    if (t < nb) partial[t] = (t == 0) ? 0 : lds[t - 1];
}

__global__ void k_scan_write(const int* __restrict__ deg, const int* __restrict__ partial,
                             int* __restrict__ rowptr, int N, int E) {
    __shared__ int lds[256];
    int t = threadIdx.x;
    int base = blockIdx.x * 1024 + t * 4;
    int v0 = 0, v1 = 0, v2 = 0, v3 = 0;
    if (base + 4 <= N) {
        int4 v = *(const int4*)&deg[base];
        v0 = v.x; v1 = v.y; v2 = v.z; v3 = v.w;
    } else {
        if (base + 0 < N) v0 = deg[base + 0];
        if (base + 1 < N) v1 = deg[base + 1];
        if (base + 2 < N) v2 = deg[base + 2];
        if (base + 3 < N) v3 = deg[base + 3];
    }
    lds[t] = v0 + v1 + v2 + v3;
    __syncthreads();
    for (int off = 1; off < 256; off <<= 1) {
        int v = (t >= off) ? lds[t - off] : 0;
        __syncthreads();
        lds[t] += v;
        __syncthreads();
    }
    int run = partial[blockIdx.x] + ((t == 0) ? 0 : lds[t - 1]);
    if (base + 0 < N) rowptr[base + 0] = run; run += v0;
    if (base + 1 < N) rowptr[base + 1] = run; run += v1;
    if (base + 2 < N) rowptr[base + 2] = run; run += v2;
    if (base + 3 < N) rowptr[base + 3] = run; run += v3;
    if (blockIdx.x == 0 && t == 0) rowptr[N] = E;
}

__global__ void k_fill(const int* ei, int* cursor, const int* rowptr, int* csr, int E) {
    int e = blockIdx.x * blockDim.x + threadIdx.x;
    if (e < E) {
        int d = ei[E + e];
        int pos = rowptr[d] + atomicAdd(&cursor[d], 1);
        csr[pos] = ei[e];
    }
}

__global__ void k_invdeg(const int* deg, float* invd, int N) {
    int i = blockIdx.x * blockDim.x + threadIdx.x;
    if (i < N) invd[i] = 1.0f / (float)max(deg[i], 1);
}

// ---------------- weight prep: concat [Wl1 | Wr1] -> bf16 [128][256] ----------------
__global__ void k_prepw(const float* __restrict__ wl, const float* __restrict__ wr,
                        unsigned short* __restrict__ wcat) {
    int i = blockIdx.x * 256 + threadIdx.x;       // 32768 total
    int o = i >> 8, k = i & 255;
    float v = (k < 128) ? wl[o * 128 + k] : wr[o * 128 + k - 128];
    wcat[i] = f2bf(v);
}

// ---------------- layer 0 (fused agg + 6->128 x2 matmul) ----------------
__global__ void k_layer0(const float* __restrict__ x, const int* __restrict__ rowptr,
                         const int* __restrict__ csr, const float* __restrict__ invd,
                         const float* __restrict__ wl, const float* __restrict__ bl,
                         const float* __restrict__ wr, float* __restrict__ out, int N) {
    int w = threadIdx.x >> 6, lid = threadIdx.x & 63;
    int n = blockIdx.x * 4 + w;
    if (n >= N) return;
    int s = rowptr[n], e = rowptr[n + 1];
    float acc = 0.f;
    if (lid < INDIM) {
        for (int i = s; i < e; i++) acc += x[csr[i] * INDIM + lid];
    }
    float id = invd[n];
    float m[INDIM], xr[INDIM];
#pragma unroll
    for (int i = 0; i < INDIM; i++) {
        m[i]  = __shfl(acc, i, 64) * id;
        xr[i] = x[n * INDIM + i];
    }
#pragma unroll
    for (int rep = 0; rep < 2; rep++) {
        int o = lid + rep * 64;
        float h = bl[o];
#pragma unroll
        for (int i = 0; i < INDIM; i++)
            h = fmaf(m[i], wl[o * INDIM + i], fmaf(xr[i], wr[o * INDIM + i], h));
        out[n * HID + o] = h;
    }
}

// ---------------- batch norm stats ----------------
__global__ void k_bnstats(const float* __restrict__ h, float* sum, float* sq, int N) {
    int t = threadIdx.x;
    int n0 = blockIdx.x * 128;
    float s = 0.f, q = 0.f;
    for (int i = 0; i < 128; i++) {
        int n = n0 + i;
        if (n < N) {
            float v = h[n * HID + t];
            s += v; q += v * v;
        }
    }
    atomicAdd(&sum[t], s);
    atomicAdd(&sq[t], q);
}

__global__ void k_bnfin(const float* sum, const float* sq, const float* g, const float* b,
                        float* scale, float* shift, float invN) {
    int t = threadIdx.x;
    float mu  = sum[t] * invN;
    float var = sq[t] * invN - mu * mu;
    float sc  = g[t] * rsqrtf(var + 1e-5f);
    scale[t] = sc;
    shift[t] = b[t] - mu * sc;
}

// ---------------- 128-dim mean aggregation with fused BN+ReLU on gathered values --------
__global__ void k_agg(const float* __restrict__ h, const int* __restrict__ rowptr,
                      const int* __restrict__ csr, const float* __restrict__ invd,
                      const float* __restrict__ scale, const float* __restrict__ shift,
                      float* __restrict__ out, int N) {
    int w = threadIdx.x >> 6, lid = threadIdx.x & 63;
    int n = blockIdx.x * 4 + w;
    if (n >= N) return;
    float2 sc = *(const float2*)&scale[lid * 2];
    float2 sh = *(const float2*)&shift[lid * 2];
    int s = rowptr[n], e = rowptr[n + 1];
    float2 acc = make_float2(0.f, 0.f);
    for (int i = s; i < e; i++) {
        int src = csr[i];
        float2 v = *(const float2*)&h[src * HID + lid * 2];
        acc.x += fmaxf(0.f, fmaf(v.x, sc.x, sh.x));
        acc.y += fmaxf(0.f, fmaf(v.y, sc.y, sh.y));
    }
    float id = invd[n];
    *(float2*)&out[n * HID + lid * 2] = make_float2(acc.x * id, acc.y * id);
}

// ---------------- MFMA double GEMM: C = Bm@Wl^T + relu(bn(Ar))@Wr^T + bias ----------------
// block: 128 rows x 128 cols, 4 waves (2x2 of 64x64), K = 256 (chunks of 32)
__global__ __launch_bounds__(256) void k_gemm(
        const float* __restrict__ Bm, const float* __restrict__ Ar,
        const unsigned short* __restrict__ wcat, const float* __restrict__ bias,
        const float* __restrict__ sc0, const float* __restrict__ sh0,
        float* __restrict__ C, int N) {
    __shared__ __align__(16) unsigned short As[128][40];   // 32 k + 8 pad
    __shared__ __align__(16) unsigned short Ws[128][40];
    int t = threadIdx.x;
    int wave = t >> 6, lane = t & 63;
    int wr = wave >> 1, wc = wave & 1;
    int row0 = blockIdx.x * 128;
    int r = t >> 1, half = t & 1;          // staging: row r, 16-col half

    f32x4 acc[4][4];
#pragma unroll
    for (int m = 0; m < 4; m++)
#pragma unroll
        for (int n = 0; n < 4; n++) acc[m][n] = (f32x4)(0.f);

    for (int chunk = 0; chunk < 8; chunk++) {
        int kb = chunk * 32;
        // ---- stage A (convert fp32 -> bf16, BN+relu for the Ar half of K) ----
        int srow = row0 + r;
        int cbase = ((kb < 128) ? kb : (kb - 128)) + half * 16;
        const float* src = (kb < 128) ? Bm : Ar;
        float xv[16];
        if (srow < N) {
            const float* p = src + (size_t)srow * HID + cbase;
            *(f4*)&xv[0]  = *(const f4*)(p + 0);
            *(f4*)&xv[4]  = *(const f4*)(p + 4);
            *(f4*)&xv[8]  = *(const f4*)(p + 8);
            *(f4*)&xv[12] = *(const f4*)(p + 12);
            if (kb >= 128) {
#pragma unroll
                for (int j = 0; j < 4; j++) {
                    f4 scv = *(const f4*)&sc0[cbase + j * 4];
                    f4 shv = *(const f4*)&sh0[cbase + j * 4];
                    xv[j*4+0] = fmaxf(0.f, fmaf(xv[j*4+0], scv.x, shv.x));
                    xv[j*4+1] = fmaxf(0.f, fmaf(xv[j*4+1], scv.y, shv.y));
                    xv[j*4+2] = fmaxf(0.f, fmaf(xv[j*4+2], scv.z, shv.z));
                    xv[j*4+3] = fmaxf(0.f, fmaf(xv[j*4+3], scv.w, shv.w));
                }
            }
        } else {
#pragma unroll
            for (int j = 0; j < 16; j++) xv[j] = 0.f;
        }
        unsigned short pk[16];
#pragma unroll
        for (int j = 0; j < 16; j++) pk[j] = f2bf(xv[j]);
        *(uint4*)&As[r][half * 16]     = *(const uint4*)&pk[0];
        *(uint4*)&As[r][half * 16 + 8] = *(const uint4*)&pk[8];
        // ---- stage W (already bf16, L2-resident) ----
        const unsigned short* wp = wcat + r * 256 + kb + half * 16;
        *(uint4*)&Ws[r][half * 16]     = *(const uint4*)(wp + 0);
        *(uint4*)&Ws[r][half * 16 + 8] = *(const uint4*)(wp + 8);
        __syncthreads();

        // ---- MFMA ----
        int lrow = lane & 15, koff = (lane >> 4) * 8;
        short8 af[4], bfr[4];
#pragma unroll
        for (int m = 0; m < 4; m++)
            af[m] = *(const short8*)&As[wr * 64 + m * 16 + lrow][koff];
#pragma unroll
        for (int n = 0; n < 4; n++)
            bfr[n] = *(const short8*)&Ws[wc * 64 + n * 16 + lrow][koff];
#pragma unroll
        for (int m = 0; m < 4; m++)
#pragma unroll
            for (int n = 0; n < 4; n++)
                acc[m][n] = __builtin_amdgcn_mfma_f32_16x16x32_bf16(af[m], bfr[n], acc[m][n], 0, 0, 0);
        __syncthreads();
    }

    // ---- epilogue: D[row][col], col = lane&15, row = (lane>>4)*4 + reg ----
    int cl = lane & 15, rq = (lane >> 4) * 4;
#pragma unroll
    for (int n = 0; n < 4; n++) {
        int col = wc * 64 + n * 16 + cl;
        float bn = bias[col];
#pragma unroll
        for (int m = 0; m < 4; m++) {
#pragma unroll
            for (int reg = 0; reg < 4; reg++) {
                int row = row0 + wr * 64 + m * 16 + rq + reg;
                if (row < N) C[(size_t)row * HID + col] = acc[m][n][reg] + bn;
            }
        }
    }
}

// ---------------- fused layer 2: BN1+relu at load + agg + dual dot + sigmoid -------------
__global__ void k_final(const float* __restrict__ h, const int* __restrict__ rowptr,
                        const int* __restrict__ csr, const float* __restrict__ invd,
                        const float* __restrict__ scale, const float* __restrict__ shift,
                        const float* __restrict__ wl2, const float* __restrict__ bl2,
                        const float* __restrict__ wr2, float* __restrict__ out, int N) {
    int w = threadIdx.x >> 6, lid = threadIdx.x & 63;
    int n = blockIdx.x * 4 + w;
    if (n >= N) return;
    float2 sc = *(const float2*)&scale[lid * 2];
    float2 sh = *(const float2*)&shift[lid * 2];
    int s = rowptr[n], e = rowptr[n + 1];
    float2 acc = make_float2(0.f, 0.f);
    for (int i = s; i < e; i++) {
        int src = csr[i];
        float2 v = *(const float2*)&h[src * HID + lid * 2];
        acc.x += fmaxf(0.f, fmaf(v.x, sc.x, sh.x));
        acc.y += fmaxf(0.f, fmaf(v.y, sc.y, sh.y));
    }
    float id = invd[n];
    float2 rootv = *(const float2*)&h[n * HID + lid * 2];
    float r0 = fmaxf(0.f, fmaf(rootv.x, sc.x, sh.x));
    float r1 = fmaxf(0.f, fmaf(rootv.y, sc.y, sh.y));
    float2 wl = *(const float2*)&wl2[lid * 2];
    float2 wrv = *(const float2*)&wr2[lid * 2];
    float p = acc.x * id * wl.x + acc.y * id * wl.y + r0 * wrv.x + r1 * wrv.y;
#pragma unroll
    for (int off = 32; off > 0; off >>= 1) p += __shfl_down(p, off, 64);
    if (lid == 0) out[n] = 1.f / (1.f + expf(-(p + bl2[0])));
}

// ---------------- host ----------------
extern "C" void kernel_launch(void* const* d_in, const int* in_sizes, int n_in,
                              void* d_out, int out_size, void* d_ws, size_t ws_size,
                              hipStream_t stream) {
    const float* x   = (const float*)d_in[0];
    const int*   ei  = (const int*)d_in[1];
    const float* wl0 = (const float*)d_in[2];
    const float* bl0 = (const float*)d_in[3];
    const float* wr0 = (const float*)d_in[4];
    const float* g0  = (const float*)d_in[5];
    const float* be0 = (const float*)d_in[6];
    const float* wl1 = (const float*)d_in[7];
    const float* bl1 = (const float*)d_in[8];
    const float* wr1 = (const float*)d_in[9];
    const float* g1  = (const float*)d_in[10];
    const float* be1 = (const float*)d_in[11];
    const float* wl2 = (const float*)d_in[12];
    const float* bl2 = (const float*)d_in[13];
    const float* wr2 = (const float*)d_in[14];
    float* outp = (float*)d_out;

    int N = in_sizes[0] / INDIM;     // 100000
    int E = in_sizes[1] / 2;         // 600000

    char* ws = (char*)d_ws;
    size_t off = 0;
    auto alloc = [&](size_t bytes) { size_t o = off; off = (off + bytes + 255) & ~(size_t)255; return o; };
    int*   degi   = (int*)(ws + alloc((size_t)N * 4));
    int*   cursor = (int*)(ws + alloc((size_t)N * 4));
    int*   rowptr = (int*)(ws + alloc((size_t)(N + 1) * 4));
    int*   csr    = (int*)(ws + alloc((size_t)E * 4));
    float* invd   = (float*)(ws + alloc((size_t)N * 4));
    int*   partial= (int*)(ws + alloc(1024 * 4));
    float* bn     = (float*)(ws + alloc(1024 * 4));
    unsigned short* wcat = (unsigned short*)(ws + alloc(128 * 256 * 2));
    float* sum0 = bn, *sq0 = bn + 128, *sum1 = bn + 256, *sq1 = bn + 384;
    float* sc0 = bn + 512, *sh0 = bn + 640, *sc1 = bn + 768, *sh1 = bn + 896;
    float* bufA = (float*)(ws + alloc((size_t)N * HID * 4));
    float* bufB = (float*)(ws + alloc((size_t)N * HID * 4));

    float invN = 1.0f / (float)N;
    int gE = (E + 255) / 256;
    int gN = (N + 255) / 256;
    int gW = (N + 3) / 4;            // wave-per-node kernels
    int gS = (N + 127) / 128;        // bnstats / gemm blocks
    int nbScan = (N + 1023) / 1024;

    // zero accumulators
    k_zero_i<<<gN, 256, 0, stream>>>(degi, N);
    k_zero_i<<<gN, 256, 0, stream>>>(cursor, N);
    k_zero_i<<<(512 + 255) / 256, 256, 0, stream>>>((int*)bn, 512);

    // weight prep (independent)
    k_prepw<<<128, 256, 0, stream>>>(wl1, wr1, wcat);

    // CSR build
    k_deg<<<gE, 256, 0, stream>>>(ei + E, degi, E);
    k_scan_partial<<<nbScan, 256, 0, stream>>>(degi, partial, N);
    k_scan_tops<<<1, 1024, 0, stream>>>(partial, nbScan);
    k_scan_write<<<nbScan, 256, 0, stream>>>(degi, partial, rowptr, N, E);
    k_fill<<<gE, 256, 0, stream>>>(ei, cursor, rowptr, csr, E);
    k_invdeg<<<gN, 256, 0, stream>>>(degi, invd, N);

    // layer 0 -> bufA (raw pre-BN)
    k_layer0<<<gW, 256, 0, stream>>>(x, rowptr, csr, invd, wl0, bl0, wr0, bufA, N);
    k_bnstats<<<gS, 128, 0, stream>>>(bufA, sum0, sq0, N);
    k_bnfin<<<1, 128, 0, stream>>>(sum0, sq0, g0, be0, sc0, sh0, invN);

    // layer 1: agg(relu(bn0(bufA)))->bufB ; MFMA gemm -> bufB in place (raw pre-BN)
    k_agg<<<gW, 256, 0, stream>>>(bufA, rowptr, csr, invd, sc0, sh0, bufB, N);
    k_gemm<<<gS, 256, 0, stream>>>(bufB, bufA, wcat, bl1, sc0, sh0, bufB, N);
    k_bnstats<<<gS, 128, 0, stream>>>(bufB, sum1, sq1, N);
    k_bnfin<<<1, 128, 0, stream>>>(sum1, sq1, g1, be1, sc1, sh1, invN);

    // layer 2 fused: BN1+relu at load + agg + dot + sigmoid -> out
    k_final<<<gW, 256, 0, stream>>>(bufB, rowptr, csr, invd, sc1, sh1, wl2, bl2, wr2, outp, N);
}

// Round 9
// 403.753 us; speedup vs baseline: 1.7180x; 1.1476x over previous
//
#include <hip/hip_runtime.h>
#include <math.h>

#define HID 128
#define INDIM 6

typedef float4 f4;
typedef __attribute__((ext_vector_type(8))) short short8;
typedef __attribute__((ext_vector_type(4))) float f32x4;

static __device__ inline unsigned short f2bf(float f) {
    union { float f; unsigned int u; } v; v.f = f;
    unsigned int r = v.u + 0x7fffu + ((v.u >> 16) & 1u);   // RNE
    return (unsigned short)(r >> 16);
}
static __device__ inline float bf2f_lo(unsigned int u) {
    union { unsigned int u; float f; } v; v.u = u << 16; return v.f;
}
static __device__ inline float bf2f_hi(unsigned int u) {
    union { unsigned int u; float f; } v; v.u = u & 0xffff0000u; return v.f;
}

// ---------------- utility ----------------
__global__ void k_zero_i(int* p, int n) {
    int i = blockIdx.x * blockDim.x + threadIdx.x;
    if (i < n) p[i] = 0;
}

// ---------------- degree ----------------
__global__ void k_deg(const int* dst, int* deg, int E) {
    int e = blockIdx.x * blockDim.x + threadIdx.x;
    if (e < E) atomicAdd(&deg[dst[e]], 1);
}

// ---------------- hierarchical exclusive scan (deg -> rowptr) ----------------
__global__ void k_scan_partial(const int* __restrict__ deg, int* __restrict__ partial, int N) {
    __shared__ int lds[256];
    int t = threadIdx.x;
    int base = blockIdx.x * 1024 + t * 4;
    int s = 0;
    if (base + 4 <= N) {
        int4 v = *(const int4*)&deg[base];
        s = v.x + v.y + v.z + v.w;
    } else {
        for (int i = 0; i < 4; i++) if (base + i < N) s += deg[base + i];
    }
    lds[t] = s;
    __syncthreads();
    for (int off = 128; off > 0; off >>= 1) {
        if (t < off) lds[t] += lds[t + off];
        __syncthreads();
    }
    if (t == 0) partial[blockIdx.x] = lds[0];
}

__global__ void k_scan_tops(int* partial, int nb) {
    __shared__ int lds[1024];
    int t = threadIdx.x;
    lds[t] = (t < nb) ? partial[t] : 0;
    __syncthreads();
    for (int off = 1; off < 1024; off <<= 1) {
        int v = (t >= off) ? lds[t - off] : 0;
        __syncthreads();
        lds[t] += v;
        __syncthreads();
    }
    if (t < nb) partial[t] = (t == 0) ? 0 : lds[t - 1];
}

__global__ void k_scan_write(const int* __restrict__ deg, const int* __restrict__ partial,
                             int* __restrict__ rowptr, int N, int E) {
    __shared__ int lds[256];
    int t = threadIdx.x;
    int base = blockIdx.x * 1024 + t * 4;
    int v0 = 0, v1 = 0, v2 = 0, v3 = 0;
    if (base + 4 <= N) {
        int4 v = *(const int4*)&deg[base];
        v0 = v.x; v1 = v.y; v2 = v.z; v3 = v.w;
    } else {
        if (base + 0 < N) v0 = deg[base + 0];
        if (base + 1 < N) v1 = deg[base + 1];
        if (base + 2 < N) v2 = deg[base + 2];
        if (base + 3 < N) v3 = deg[base + 3];
    }
    lds[t] = v0 + v1 + v2 + v3;
    __syncthreads();
    for (int off = 1; off < 256; off <<= 1) {
        int v = (t >= off) ? lds[t - off] : 0;
        __syncthreads();
        lds[t] += v;
        __syncthreads();
    }
    int run = partial[blockIdx.x] + ((t == 0) ? 0 : lds[t - 1]);
    if (base + 0 < N) rowptr[base + 0] = run; run += v0;
    if (base + 1 < N) rowptr[base + 1] = run; run += v1;
    if (base + 2 < N) rowptr[base + 2] = run; run += v2;
    if (base + 3 < N) rowptr[base + 3] = run; run += v3;
    if (blockIdx.x == 0 && t == 0) rowptr[N] = E;
}

__global__ void k_fill(const int* ei, int* cursor, const int* rowptr, int* csr, int E) {
    int e = blockIdx.x * blockDim.x + threadIdx.x;
    if (e < E) {
        int d = ei[E + e];
        int pos = rowptr[d] + atomicAdd(&cursor[d], 1);
        csr[pos] = ei[e];
    }
}

__global__ void k_invdeg(const int* deg, float* invd, int N) {
    int i = blockIdx.x * blockDim.x + threadIdx.x;
    if (i < N) invd[i] = 1.0f / (float)max(deg[i], 1);
}

// ---------------- weight prep: concat [Wl1 | Wr1] -> bf16 [128][256] ----------------
__global__ void k_prepw(const float* __restrict__ wl, const float* __restrict__ wr,
                        unsigned short* __restrict__ wcat) {
    int i = blockIdx.x * 256 + threadIdx.x;       // 32768 total
    int o = i >> 8, k = i & 255;
    float v = (k < 128) ? wl[o * 128 + k] : wr[o * 128 + k - 128];
    wcat[i] = f2bf(v);
}

// ---------------- layer 0 (fused agg + 6->128 x2 matmul) ----------------
__global__ void k_layer0(const float* __restrict__ x, const int* __restrict__ rowptr,
                         const int* __restrict__ csr, const float* __restrict__ invd,
                         const float* __restrict__ wl, const float* __restrict__ bl,
                         const float* __restrict__ wr, float* __restrict__ out, int N) {
    int w = threadIdx.x >> 6, lid = threadIdx.x & 63;
    int n = blockIdx.x * 4 + w;
    if (n >= N) return;
    int s = rowptr[n], e = rowptr[n + 1];
    float acc = 0.f;
    if (lid < INDIM) {
        for (int i = s; i < e; i++) acc += x[csr[i] * INDIM + lid];
    }
    float id = invd[n];
    float m[INDIM], xr[INDIM];
#pragma unroll
    for (int i = 0; i < INDIM; i++) {
        m[i]  = __shfl(acc, i, 64) * id;
        xr[i] = x[n * INDIM + i];
    }
#pragma unroll
    for (int rep = 0; rep < 2; rep++) {
        int o = lid + rep * 64;
        float h = bl[o];
#pragma unroll
        for (int i = 0; i < INDIM; i++)
            h = fmaf(m[i], wl[o * INDIM + i], fmaf(xr[i], wr[o * INDIM + i], h));
        out[n * HID + o] = h;
    }
}

// ---------------- batch norm stats ----------------
__global__ void k_bnstats(const float* __restrict__ h, float* sum, float* sq, int N) {
    int t = threadIdx.x;
    int n0 = blockIdx.x * 128;
    float s = 0.f, q = 0.f;
    for (int i = 0; i < 128; i++) {
        int n = n0 + i;
        if (n < N) {
            float v = h[n * HID + t];
            s += v; q += v * v;
        }
    }
    atomicAdd(&sum[t], s);
    atomicAdd(&sq[t], q);
}

__global__ void k_bnfin(const float* sum, const float* sq, const float* g, const float* b,
                        float* scale, float* shift, float invN) {
    int t = threadIdx.x;
    float mu  = sum[t] * invN;
    float var = sq[t] * invN - mu * mu;
    float sc  = g[t] * rsqrtf(var + 1e-5f);
    scale[t] = sc;
    shift[t] = b[t] - mu * sc;
}

// ---------------- apply BN+ReLU, emit bf16 rows ----------------
__global__ void k_bnapply(const float* __restrict__ h, const float* __restrict__ scale,
                          const float* __restrict__ shift, unsigned short* __restrict__ out,
                          int total8) {
    int i = blockIdx.x * blockDim.x + threadIdx.x;
    int stride = gridDim.x * blockDim.x;
    for (; i < total8; i += stride) {
        int f8 = (i & 15) * 8;                    // 16 groups of 8 per 128-feature row
        f4 v0 = ((const f4*)h)[i * 2];
        f4 v1 = ((const f4*)h)[i * 2 + 1];
        f4 sc0v = *(const f4*)&scale[f8];
        f4 sc1v = *(const f4*)&scale[f8 + 4];
        f4 sh0v = *(const f4*)&shift[f8];
        f4 sh1v = *(const f4*)&shift[f8 + 4];
        unsigned short pk[8];
        pk[0] = f2bf(fmaxf(0.f, fmaf(v0.x, sc0v.x, sh0v.x)));
        pk[1] = f2bf(fmaxf(0.f, fmaf(v0.y, sc0v.y, sh0v.y)));
        pk[2] = f2bf(fmaxf(0.f, fmaf(v0.z, sc0v.z, sh0v.z)));
        pk[3] = f2bf(fmaxf(0.f, fmaf(v0.w, sc0v.w, sh0v.w)));
        pk[4] = f2bf(fmaxf(0.f, fmaf(v1.x, sc1v.x, sh1v.x)));
        pk[5] = f2bf(fmaxf(0.f, fmaf(v1.y, sc1v.y, sh1v.y)));
        pk[6] = f2bf(fmaxf(0.f, fmaf(v1.z, sc1v.z, sh1v.z)));
        pk[7] = f2bf(fmaxf(0.f, fmaf(v1.w, sc1v.w, sh1v.w)));
        *(uint4*)&out[(size_t)i * 8] = *(const uint4*)pk;
    }
}

// ---------------- bf16 mean aggregation (CSR gather, wave per node) ----------------
__global__ void k_agg_bf(const unsigned short* __restrict__ hb, const int* __restrict__ rowptr,
                         const int* __restrict__ csr, const float* __restrict__ invd,
                         unsigned short* __restrict__ out, int N) {
    int w = threadIdx.x >> 6, lid = threadIdx.x & 63;
    int n = blockIdx.x * 4 + w;
    if (n >= N) return;
    int s = rowptr[n], e = rowptr[n + 1];
    const unsigned int* hb32 = (const unsigned int*)hb;
    float ax = 0.f, ay = 0.f;
    for (int i = s; i < e; i++) {
        int src = csr[i];
        unsigned int u = hb32[(size_t)src * 64 + lid];
        ax += bf2f_lo(u);
        ay += bf2f_hi(u);
    }
    float id = invd[n];
    unsigned int r = (unsigned int)f2bf(ax * id) | ((unsigned int)f2bf(ay * id) << 16);
    ((unsigned int*)out)[(size_t)n * 64 + lid] = r;
}

// ---------------- MFMA double GEMM (all-bf16 inputs): C = Bm@Wl^T + Ar@Wr^T + bias ------
// block: 128 rows x 128 cols, 4 waves (2x2 of 64x64), K = 256 (chunks of 32)
__global__ __launch_bounds__(256) void k_gemm(
        const unsigned short* __restrict__ Bm, const unsigned short* __restrict__ Ar,
        const unsigned short* __restrict__ wcat, const float* __restrict__ bias,
        float* __restrict__ C, int N) {
    __shared__ __align__(16) unsigned short As[128][40];   // 32 k + 8 pad
    __shared__ __align__(16) unsigned short Ws[128][40];
    int t = threadIdx.x;
    int wave = t >> 6, lane = t & 63;
    int wr = wave >> 1, wc = wave & 1;
    int row0 = blockIdx.x * 128;
    int r = t >> 1, half = t & 1;          // staging: row r, 16-col half

    f32x4 acc[4][4];
#pragma unroll
    for (int m = 0; m < 4; m++)
#pragma unroll
        for (int n = 0; n < 4; n++) acc[m][n] = (f32x4)(0.f);

    for (int chunk = 0; chunk < 8; chunk++) {
        int kb = chunk * 32;
        // ---- stage A (bf16 copy) ----
        int srow = row0 + r;
        int c0 = (chunk & 3) * 32 + half * 16;
        const unsigned short* src = (chunk < 4) ? Bm : Ar;
        if (srow < N) {
            const unsigned short* p = src + (size_t)srow * HID + c0;
            *(uint4*)&As[r][half * 16]     = *(const uint4*)(p);
            *(uint4*)&As[r][half * 16 + 8] = *(const uint4*)(p + 8);
        } else {
            uint4 z = make_uint4(0, 0, 0, 0);
            *(uint4*)&As[r][half * 16]     = z;
            *(uint4*)&As[r][half * 16 + 8] = z;
        }
        // ---- stage W (bf16, L2-resident) ----
        const unsigned short* wp = wcat + r * 256 + kb + half * 16;
        *(uint4*)&Ws[r][half * 16]     = *(const uint4*)(wp + 0);
        *(uint4*)&Ws[r][half * 16 + 8] = *(const uint4*)(wp + 8);
        __syncthreads();

        // ---- MFMA ----
        int lrow = lane & 15, koff = (lane >> 4) * 8;
        short8 af[4], bfr[4];
#pragma unroll
        for (int m = 0; m < 4; m++)
            af[m] = *(const short8*)&As[wr * 64 + m * 16 + lrow][koff];
#pragma unroll
        for (int n = 0; n < 4; n++)
            bfr[n] = *(const short8*)&Ws[wc * 64 + n * 16 + lrow][koff];
#pragma unroll
        for (int m = 0; m < 4; m++)
#pragma unroll
            for (int n = 0; n < 4; n++)
                acc[m][n] = __builtin_amdgcn_mfma_f32_16x16x32_bf16(af[m], bfr[n], acc[m][n], 0, 0, 0);
        __syncthreads();
    }

    // ---- epilogue: D[row][col], col = lane&15, row = (lane>>4)*4 + reg ----
    int cl = lane & 15, rq = (lane >> 4) * 4;
#pragma unroll
    for (int n = 0; n < 4; n++) {
        int col = wc * 64 + n * 16 + cl;
        float bn = bias[col];
#pragma unroll
        for (int m = 0; m < 4; m++) {
#pragma unroll
            for (int reg = 0; reg < 4; reg++) {
                int row = row0 + wr * 64 + m * 16 + rq + reg;
                if (row < N) C[(size_t)row * HID + col] = acc[m][n][reg] + bn;
            }
        }
    }
}

// ---------------- layer 2 dots: s = relu(bn1(h))·wl2, r = relu(bn1(h))·wr2 ----------------
__global__ void k_dots(const float* __restrict__ h, const float* __restrict__ scale,
                       const float* __restrict__ shift, const float* __restrict__ wl2,
                       const float* __restrict__ wr2, float* __restrict__ s_arr,
                       float* __restrict__ r_arr, int N) {
    int w = threadIdx.x >> 6, lid = threadIdx.x & 63;
    int n = blockIdx.x * 4 + w;
    if (n >= N) return;
    float2 v  = *(const float2*)&h[(size_t)n * HID + lid * 2];
    float2 sc = *(const float2*)&scale[lid * 2];
    float2 sh = *(const float2*)&shift[lid * 2];
    float y0 = fmaxf(0.f, fmaf(v.x, sc.x, sh.x));
    float y1 = fmaxf(0.f, fmaf(v.y, sc.y, sh.y));
    float2 wl = *(const float2*)&wl2[lid * 2];
    float2 wrv = *(const float2*)&wr2[lid * 2];
    float ps = y0 * wl.x + y1 * wl.y;
    float pr = y0 * wrv.x + y1 * wrv.y;
#pragma unroll
    for (int off = 32; off > 0; off >>= 1) {
        ps += __shfl_down(ps, off, 64);
        pr += __shfl_down(pr, off, 64);
    }
    if (lid == 0) { s_arr[n] = ps; r_arr[n] = pr; }
}

// ---------------- final: scalar mean over edges + sigmoid ----------------
__global__ void k_final2(const float* __restrict__ s_arr, const float* __restrict__ r_arr,
                         const int* __restrict__ rowptr, const int* __restrict__ csr,
                         const float* __restrict__ invd, const float* __restrict__ bl2,
                         float* __restrict__ out, int N) {
    int n = blockIdx.x * blockDim.x + threadIdx.x;
    if (n >= N) return;
    int s = rowptr[n], e = rowptr[n + 1];
    float a = 0.f;
    for (int i = s; i < e; i++) a += s_arr[csr[i]];
    float p = a * invd[n] + r_arr[n] + bl2[0];
    out[n] = 1.f / (1.f + expf(-p));
}

// ---------------- host ----------------
extern "C" void kernel_launch(void* const* d_in, const int* in_sizes, int n_in,
                              void* d_out, int out_size, void* d_ws, size_t ws_size,
                              hipStream_t stream) {
    const float* x   = (const float*)d_in[0];
    const int*   ei  = (const int*)d_in[1];
    const float* wl0 = (const float*)d_in[2];
    const float* bl0 = (const float*)d_in[3];
    const float* wr0 = (const float*)d_in[4];
    const float* g0  = (const float*)d_in[5];
    const float* be0 = (const float*)d_in[6];
    const float* wl1 = (const float*)d_in[7];
    const float* bl1 = (const float*)d_in[8];
    const float* wr1 = (const float*)d_in[9];
    const float* g1  = (const float*)d_in[10];
    const float* be1 = (const float*)d_in[11];
    const float* wl2 = (const float*)d_in[12];
    const float* bl2 = (const float*)d_in[13];
    const float* wr2 = (const float*)d_in[14];
    float* outp = (float*)d_out;

    int N = in_sizes[0] / INDIM;     // 100000
    int E = in_sizes[1] / 2;         // 600000

    char* ws = (char*)d_ws;
    size_t off = 0;
    auto alloc = [&](size_t bytes) { size_t o = off; off = (off + bytes + 255) & ~(size_t)255; return o; };
    int*   degi   = (int*)(ws + alloc((size_t)N * 4));
    int*   cursor = (int*)(ws + alloc((size_t)N * 4));
    int*   rowptr = (int*)(ws + alloc((size_t)(N + 1) * 4));
    int*   csr    = (int*)(ws + alloc((size_t)E * 4));
    float* invd   = (float*)(ws + alloc((size_t)N * 4));
    int*   partial= (int*)(ws + alloc(1024 * 4));
    float* bn     = (float*)(ws + alloc(1024 * 4));
    unsigned short* wcat = (unsigned short*)(ws + alloc(128 * 256 * 2));
    float* sarr   = (float*)(ws + alloc((size_t)N * 4));
    float* rarr   = (float*)(ws + alloc((size_t)N * 4));
    float* sum0 = bn, *sq0 = bn + 128, *sum1 = bn + 256, *sq1 = bn + 384;
    float* sc0 = bn + 512, *sh0 = bn + 640, *sc1 = bn + 768, *sh1 = bn + 896;
    float* bufA = (float*)(ws + alloc((size_t)N * HID * 4));            // layer0 raw out
    float* bufB = (float*)(ws + alloc((size_t)N * HID * 4));            // gemm out (raw pre-BN1)
    unsigned short* bufC = (unsigned short*)(ws + alloc((size_t)N * HID * 2)); // bf16 relu(bn0)
    unsigned short* bufD = (unsigned short*)bufA;                       // bf16 agg mean (aliases dead bufA)

    float invN = 1.0f / (float)N;
    int gE = (E + 255) / 256;
    int gN = (N + 255) / 256;
    int gW = (N + 3) / 4;            // wave-per-node kernels
    int gS = (N + 127) / 128;        // bnstats / gemm blocks
    int nbScan = (N + 1023) / 1024;
    int total8 = N * (HID / 8);

    // zero accumulators
    k_zero_i<<<gN, 256, 0, stream>>>(degi, N);
    k_zero_i<<<gN, 256, 0, stream>>>(cursor, N);
    k_zero_i<<<(512 + 255) / 256, 256, 0, stream>>>((int*)bn, 512);

    // weight prep (independent)
    k_prepw<<<128, 256, 0, stream>>>(wl1, wr1, wcat);

    // CSR build
    k_deg<<<gE, 256, 0, stream>>>(ei + E, degi, E);
    k_scan_partial<<<nbScan, 256, 0, stream>>>(degi, partial, N);
    k_scan_tops<<<1, 1024, 0, stream>>>(partial, nbScan);
    k_scan_write<<<nbScan, 256, 0, stream>>>(degi, partial, rowptr, N, E);
    k_fill<<<gE, 256, 0, stream>>>(ei, cursor, rowptr, csr, E);
    k_invdeg<<<gN, 256, 0, stream>>>(degi, invd, N);

    // layer 0 -> bufA (raw pre-BN)
    k_layer0<<<gW, 256, 0, stream>>>(x, rowptr, csr, invd, wl0, bl0, wr0, bufA, N);
    k_bnstats<<<gS, 128, 0, stream>>>(bufA, sum0, sq0, N);
    k_bnfin<<<1, 128, 0, stream>>>(sum0, sq0, g0, be0, sc0, sh0, invN);

    // bf16 relu(bn0(bufA)) -> bufC ; after this bufA is dead (bufD aliases it)
    k_bnapply<<<2048, 256, 0, stream>>>(bufA, sc0, sh0, bufC, total8);

    // layer 1: agg(bufC) -> bufD (bf16) ; MFMA gemm(bufD, bufC) -> bufB (raw pre-BN1)
    k_agg_bf<<<gW, 256, 0, stream>>>(bufC, rowptr, csr, invd, bufD, N);
    k_gemm<<<gS, 256, 0, stream>>>(bufD, bufC, wcat, bl1, bufB, N);
    k_bnstats<<<gS, 128, 0, stream>>>(bufB, sum1, sq1, N);
    k_bnfin<<<1, 128, 0, stream>>>(sum1, sq1, g1, be1, sc1, sh1, invN);

    // layer 2: per-node dots then scalar aggregation + sigmoid
    k_dots<<<gW, 256, 0, stream>>>(bufB, sc1, sh1, wl2, wr2, sarr, rarr, N);
    k_final2<<<gN, 256, 0, stream>>>(sarr, rarr, rowptr, csr, invd, bl2, outp, N);
}

// Round 10
// 277.832 us; speedup vs baseline: 2.4967x; 1.4532x over previous
//
#include <hip/hip_runtime.h>
#include <math.h>

#define HID 128
#define INDIM 6

typedef float4 f4;
typedef __attribute__((ext_vector_type(8))) short short8;
typedef __attribute__((ext_vector_type(4))) float f32x4;

static __device__ inline unsigned short f2bf(float f) {
    union { float f; unsigned int u; } v; v.f = f;
    unsigned int r = v.u + 0x7fffu + ((v.u >> 16) & 1u);   // RNE
    return (unsigned short)(r >> 16);
}
static __device__ inline float bf2f_lo(unsigned int u) {
    union { unsigned int u; float f; } v; v.u = u << 16; return v.f;
}
static __device__ inline float bf2f_hi(unsigned int u) {
    union { unsigned int u; float f; } v; v.u = u & 0xffff0000u; return v.f;
}

// ---------------- utility ----------------
__global__ void k_zero_i(int* p, int n) {
    int i = blockIdx.x * blockDim.x + threadIdx.x;
    if (i < n) p[i] = 0;
}

// ---------------- degree ----------------
__global__ void k_deg(const int* dst, int* deg, int E) {
    int e = blockIdx.x * blockDim.x + threadIdx.x;
    if (e < E) atomicAdd(&deg[dst[e]], 1);
}

// ---------------- hierarchical exclusive scan (deg -> rowptr) ----------------
__global__ void k_scan_partial(const int* __restrict__ deg, int* __restrict__ partial, int N) {
    __shared__ int lds[256];
    int t = threadIdx.x;
    int base = blockIdx.x * 1024 + t * 4;
    int s = 0;
    if (base + 4 <= N) {
        int4 v = *(const int4*)&deg[base];
        s = v.x + v.y + v.z + v.w;
    } else {
        for (int i = 0; i < 4; i++) if (base + i < N) s += deg[base + i];
    }
    lds[t] = s;
    __syncthreads();
    for (int off = 128; off > 0; off >>= 1) {
        if (t < off) lds[t] += lds[t + off];
        __syncthreads();
    }
    if (t == 0) partial[blockIdx.x] = lds[0];
}

__global__ void k_scan_tops(int* partial, int nb) {
    __shared__ int lds[1024];
    int t = threadIdx.x;
    lds[t] = (t < nb) ? partial[t] : 0;
    __syncthreads();
    for (int off = 1; off < 1024; off <<= 1) {
        int v = (t >= off) ? lds[t - off] : 0;
        __syncthreads();
        lds[t] += v;
        __syncthreads();
    }
    if (t < nb) partial[t] = (t == 0) ? 0 : lds[t - 1];
}

__global__ void k_scan_write(const int* __restrict__ deg, const int* __restrict__ partial,
                             int* __restrict__ rowptr, int N, int E) {
    __shared__ int lds[256];
    int t = threadIdx.x;
    int base = blockIdx.x * 1024 + t * 4;
    int v0 = 0, v1 = 0, v2 = 0, v3 = 0;
    if (base + 4 <= N) {
        int4 v = *(const int4*)&deg[base];
        v0 = v.x; v1 = v.y; v2 = v.z; v3 = v.w;
    } else {
        if (base + 0 < N) v0 = deg[base + 0];
        if (base + 1 < N) v1 = deg[base + 1];
        if (base + 2 < N) v2 = deg[base + 2];
        if (base + 3 < N) v3 = deg[base + 3];
    }
    lds[t] = v0 + v1 + v2 + v3;
    __syncthreads();
    for (int off = 1; off < 256; off <<= 1) {
        int v = (t >= off) ? lds[t - off] : 0;
        __syncthreads();
        lds[t] += v;
        __syncthreads();
    }
    int run = partial[blockIdx.x] + ((t == 0) ? 0 : lds[t - 1]);
    if (base + 0 < N) rowptr[base + 0] = run; run += v0;
    if (base + 1 < N) rowptr[base + 1] = run; run += v1;
    if (base + 2 < N) rowptr[base + 2] = run; run += v2;
    if (base + 3 < N) rowptr[base + 3] = run; run += v3;
    if (blockIdx.x == 0 && t == 0) rowptr[N] = E;
}

__global__ void k_fill(const int* ei, int* cursor, const int* rowptr, int* csr, int E) {
    int e = blockIdx.x * blockDim.x + threadIdx.x;
    if (e < E) {
        int d = ei[E + e];
        int pos = rowptr[d] + atomicAdd(&cursor[d], 1);
        csr[pos] = ei[e];
    }
}

__global__ void k_invdeg(const int* deg, float* invd, int N) {
    int i = blockIdx.x * blockDim.x + threadIdx.x;
    if (i < N) invd[i] = 1.0f / (float)max(deg[i], 1);
}

// ---------------- weight prep: concat [Wl1 | Wr1] -> bf16 [128][256] ----------------
__global__ void k_prepw(const float* __restrict__ wl, const float* __restrict__ wr,
                        unsigned short* __restrict__ wcat) {
    int i = blockIdx.x * 256 + threadIdx.x;       // 32768 total
    int o = i >> 8, k = i & 255;
    float v = (k < 128) ? wl[o * 128 + k] : wr[o * 128 + k - 128];
    wcat[i] = f2bf(v);
}

// ---------------- layer 0: agg + 6->128 x2 matmul + fused BN stats ----------------
// 32 nodes/block, 8 threads/node (6 active in gather). LDS-staged padded weights.
__global__ __launch_bounds__(256) void k_layer0(
        const float* __restrict__ x, const int* __restrict__ rowptr,
        const int* __restrict__ csr, const float* __restrict__ invd,
        const float* __restrict__ wl, const float* __restrict__ bl,
        const float* __restrict__ wr, float* __restrict__ out,
        float* __restrict__ sum8, float* __restrict__ sq8, int N) {
    __shared__ float wlds[1600];   // [wl | wr], addr = base + o*6+i + (o>>4)*2  (bank-spread)
    __shared__ float blds[136];    // bias, addr = o + (o>>4)
    __shared__ float mx[32][8];
    __shared__ float xr[32][8];
    __shared__ float ps[4][128];
    __shared__ float pq[4][128];
    int t = threadIdx.x;
    for (int idx = t; idx < 1536; idx += 256) {
        int half = idx >= 768 ? 1 : 0;
        int lin = idx - half * 768;
        int o = lin / 6, i = lin - o * 6;
        float v = half ? wr[lin] : wl[lin];
        wlds[half * 800 + o * 6 + i + (o >> 4) * 2] = v;
    }
    if (t < 128) blds[t + (t >> 4)] = bl[t];
    int nl = t >> 3, f = t & 7;
    int n = blockIdx.x * 32 + nl;
    bool valid = n < N;
    if (f < 6) {
        float mean = 0.f, xv = 0.f;
        if (valid) {
            int s = rowptr[n], e = rowptr[n + 1];
            float acc = 0.f;
            for (int i = s; i < e; i++) acc += x[csr[i] * 6 + f];
            mean = acc * invd[n];
            xv = x[n * 6 + f];
        }
        mx[nl][f] = mean;
        xr[nl][f] = xv;
    }
    __syncthreads();
    float m0 = mx[nl][0], m1 = mx[nl][1], m2 = mx[nl][2];
    float m3 = mx[nl][3], m4 = mx[nl][4], m5 = mx[nl][5];
    float r0 = xr[nl][0], r1 = xr[nl][1], r2 = xr[nl][2];
    float r3 = xr[nl][3], r4 = xr[nl][4], r5 = xr[nl][5];
    const float* wA = wlds;
    const float* wB = wlds + 800;
    float sk[16], qk[16];
#pragma unroll
    for (int k4 = 0; k4 < 4; k4++) {
        f4 hv;
        float* hp = &hv.x;
#pragma unroll
        for (int j = 0; j < 4; j++) {
            int k = k4 * 4 + j;
            int o = f * 16 + k;
            int wb = 98 * f + 6 * k;            // o*6 + (o>>4)*2
            float h = blds[o + f];              // o + (o>>4), o>>4 == f
            h += m0 * wA[wb] + m1 * wA[wb + 1] + m2 * wA[wb + 2]
               + m3 * wA[wb + 3] + m4 * wA[wb + 4] + m5 * wA[wb + 5];
            h += r0 * wB[wb] + r1 * wB[wb + 1] + r2 * wB[wb + 2]
               + r3 * wB[wb + 3] + r4 * wB[wb + 4] + r5 * wB[wb + 5];
            hp[j] = h;
            float hs = valid ? h : 0.f;
            sk[k] = hs;
            qk[k] = hs * hs;
        }
        if (valid) *(f4*)&out[(size_t)n * HID + f * 16 + k4 * 4] = hv;
    }
    // stats: reduce over the wave's 8 nodes (lane bits 3..5), then LDS, then 8-copy atomics
    int wv = t >> 6, lane = t & 63;
#pragma unroll
    for (int k = 0; k < 16; k++) {
        float s = sk[k], q = qk[k];
        s += __shfl_xor(s, 8, 64);  q += __shfl_xor(q, 8, 64);
        s += __shfl_xor(s, 16, 64); q += __shfl_xor(q, 16, 64);
        s += __shfl_xor(s, 32, 64); q += __shfl_xor(q, 32, 64);
        if (lane < 8) { ps[wv][lane * 16 + k] = s; pq[wv][lane * 16 + k] = q; }
    }
    __syncthreads();
    if (t < 128) {
        float S = ps[0][t] + ps[1][t] + ps[2][t] + ps[3][t];
        float Q = pq[0][t] + pq[1][t] + pq[2][t] + pq[3][t];
        int slot = (blockIdx.x & 7) * 128 + t;
        atomicAdd(&sum8[slot], S);
        atomicAdd(&sq8[slot], Q);
    }
}

// ---------------- BN finalize from 8-copy accumulators ----------------
__global__ void k_bnfin8(const float* sum8, const float* sq8, const float* g, const float* b,
                         float* scale, float* shift, float invN) {
    int t = threadIdx.x;
    float s = 0.f, q = 0.f;
    for (int c = 0; c < 8; c++) { s += sum8[c * 128 + t]; q += sq8[c * 128 + t]; }
    float mu  = s * invN;
    float var = q * invN - mu * mu;
    float sc  = g[t] * rsqrtf(var + 1e-5f);
    scale[t] = sc;
    shift[t] = b[t] - mu * sc;
}

// ---------------- apply BN+ReLU, emit bf16 rows ----------------
__global__ void k_bnapply(const float* __restrict__ h, const float* __restrict__ scale,
                          const float* __restrict__ shift, unsigned short* __restrict__ out,
                          int total8) {
    int i = blockIdx.x * blockDim.x + threadIdx.x;
    int stride = gridDim.x * blockDim.x;
    for (; i < total8; i += stride) {
        int f8 = (i & 15) * 8;
        f4 v0 = ((const f4*)h)[i * 2];
        f4 v1 = ((const f4*)h)[i * 2 + 1];
        f4 sc0v = *(const f4*)&scale[f8];
        f4 sc1v = *(const f4*)&scale[f8 + 4];
        f4 sh0v = *(const f4*)&shift[f8];
        f4 sh1v = *(const f4*)&shift[f8 + 4];
        unsigned short pk[8];
        pk[0] = f2bf(fmaxf(0.f, fmaf(v0.x, sc0v.x, sh0v.x)));
        pk[1] = f2bf(fmaxf(0.f, fmaf(v0.y, sc0v.y, sh0v.y)));
        pk[2] = f2bf(fmaxf(0.f, fmaf(v0.z, sc0v.z, sh0v.z)));
        pk[3] = f2bf(fmaxf(0.f, fmaf(v0.w, sc0v.w, sh0v.w)));
        pk[4] = f2bf(fmaxf(0.f, fmaf(v1.x, sc1v.x, sh1v.x)));
        pk[5] = f2bf(fmaxf(0.f, fmaf(v1.y, sc1v.y, sh1v.y)));
        pk[6] = f2bf(fmaxf(0.f, fmaf(v1.z, sc1v.z, sh1v.z)));
        pk[7] = f2bf(fmaxf(0.f, fmaf(v1.w, sc1v.w, sh1v.w)));
        *(uint4*)&out[(size_t)i * 8] = *(const uint4*)pk;
    }
}

// ---------------- bf16 mean aggregation (CSR gather, wave per node) ----------------
__global__ void k_agg_bf(const unsigned short* __restrict__ hb, const int* __restrict__ rowptr,
                         const int* __restrict__ csr, const float* __restrict__ invd,
                         unsigned short* __restrict__ out, int N) {
    int w = threadIdx.x >> 6, lid = threadIdx.x & 63;
    int n = blockIdx.x * 4 + w;
    if (n >= N) return;
    int s = rowptr[n], e = rowptr[n + 1];
    const unsigned int* hb32 = (const unsigned int*)hb;
    float ax = 0.f, ay = 0.f;
    for (int i = s; i < e; i++) {
        int src = csr[i];
        unsigned int u = hb32[(size_t)src * 64 + lid];
        ax += bf2f_lo(u);
        ay += bf2f_hi(u);
    }
    float id = invd[n];
    unsigned int r = (unsigned int)f2bf(ax * id) | ((unsigned int)f2bf(ay * id) << 16);
    ((unsigned int*)out)[(size_t)n * 64 + lid] = r;
}

// ---------------- MFMA double GEMM + fused BN1 stats ----------------
// block: 128 rows x 128 cols, 4 waves (2x2 of 64x64), K = 256 (chunks of 32)
__global__ __launch_bounds__(256) void k_gemm(
        const unsigned short* __restrict__ Bm, const unsigned short* __restrict__ Ar,
        const unsigned short* __restrict__ wcat, const float* __restrict__ bias,
        float* __restrict__ sum8, float* __restrict__ sq8,
        float* __restrict__ C, int N) {
    __shared__ __align__(16) unsigned short As[128][40];   // 32 k + 8 pad
    __shared__ __align__(16) unsigned short Ws[128][40];
    __shared__ float lds_s[2][128];
    __shared__ float lds_q[2][128];
    int t = threadIdx.x;
    int wave = t >> 6, lane = t & 63;
    int wr = wave >> 1, wc = wave & 1;
    int row0 = blockIdx.x * 128;
    int r = t >> 1, half = t & 1;          // staging: row r, 16-col half

    f32x4 acc[4][4];
#pragma unroll
    for (int m = 0; m < 4; m++)
#pragma unroll
        for (int n = 0; n < 4; n++) acc[m][n] = (f32x4)(0.f);

    for (int chunk = 0; chunk < 8; chunk++) {
        int kb = chunk * 32;
        // ---- stage A (bf16 copy) ----
        int srow = row0 + r;
        int c0 = (chunk & 3) * 32 + half * 16;
        const unsigned short* src = (chunk < 4) ? Bm : Ar;
        if (srow < N) {
            const unsigned short* p = src + (size_t)srow * HID + c0;
            *(uint4*)&As[r][half * 16]     = *(const uint4*)(p);
            *(uint4*)&As[r][half * 16 + 8] = *(const uint4*)(p + 8);
        } else {
            uint4 z = make_uint4(0, 0, 0, 0);
            *(uint4*)&As[r][half * 16]     = z;
            *(uint4*)&As[r][half * 16 + 8] = z;
        }
        // ---- stage W (bf16, L2-resident) ----
        const unsigned short* wp = wcat + r * 256 + kb + half * 16;
        *(uint4*)&Ws[r][half * 16]     = *(const uint4*)(wp + 0);
        *(uint4*)&Ws[r][half * 16 + 8] = *(const uint4*)(wp + 8);
        __syncthreads();

        // ---- MFMA ----
        int lrow = lane & 15, koff = (lane >> 4) * 8;
        short8 af[4], bfr[4];
#pragma unroll
        for (int m = 0; m < 4; m++)
            af[m] = *(const short8*)&As[wr * 64 + m * 16 + lrow][koff];
#pragma unroll
        for (int n = 0; n < 4; n++)
            bfr[n] = *(const short8*)&Ws[wc * 64 + n * 16 + lrow][koff];
#pragma unroll
        for (int m = 0; m < 4; m++)
#pragma unroll
            for (int n = 0; n < 4; n++)
                acc[m][n] = __builtin_amdgcn_mfma_f32_16x16x32_bf16(af[m], bfr[n], acc[m][n], 0, 0, 0);
        __syncthreads();
    }

    // ---- epilogue: store + per-col stats. D: col = lane&15, row = (lane>>4)*4 + reg ----
    int cl = lane & 15, rq = (lane >> 4) * 4;
    float cs[4], cq[4];
#pragma unroll
    for (int n = 0; n < 4; n++) {
        int col = wc * 64 + n * 16 + cl;
        float bn = bias[col];
        float s = 0.f, q = 0.f;
#pragma unroll
        for (int m = 0; m < 4; m++) {
#pragma unroll
            for (int reg = 0; reg < 4; reg++) {
                int row = row0 + wr * 64 + m * 16 + rq + reg;
                float v = acc[m][n][reg] + bn;
                if (row < N) {
                    C[(size_t)row * HID + col] = v;
                    s += v;
                    q += v * v;
                }
            }
        }
        cs[n] = s; cq[n] = q;
    }
#pragma unroll
    for (int n = 0; n < 4; n++) {
        float s = cs[n], q = cq[n];
        s += __shfl_xor(s, 16, 64); q += __shfl_xor(q, 16, 64);
        s += __shfl_xor(s, 32, 64); q += __shfl_xor(q, 32, 64);
        if (lane < 16) {
            int col = wc * 64 + n * 16 + cl;   // cl == lane
            lds_s[wr][col] = s;
            lds_q[wr][col] = q;
        }
    }
    __syncthreads();
    if (t < 128) {
        float S = lds_s[0][t] + lds_s[1][t];
        float Q = lds_q[0][t] + lds_q[1][t];
        int slot = (blockIdx.x & 7) * 128 + t;
        atomicAdd(&sum8[slot], S);
        atomicAdd(&sq8[slot], Q);
    }
}

// ---------------- layer 2 dots: s = relu(bn1(h))·wl2, r = relu(bn1(h))·wr2 ----------------
__global__ void k_dots(const float* __restrict__ h, const float* __restrict__ scale,
                       const float* __restrict__ shift, const float* __restrict__ wl2,
                       const float* __restrict__ wr2, float* __restrict__ s_arr,
                       float* __restrict__ r_arr, int N) {
    int w = threadIdx.x >> 6, lid = threadIdx.x & 63;
    int n = blockIdx.x * 4 + w;
    if (n >= N) return;
    float2 v  = *(const float2*)&h[(size_t)n * HID + lid * 2];
    float2 sc = *(const float2*)&scale[lid * 2];
    float2 sh = *(const float2*)&shift[lid * 2];
    float y0 = fmaxf(0.f, fmaf(v.x, sc.x, sh.x));
    float y1 = fmaxf(0.f, fmaf(v.y, sc.y, sh.y));
    float2 wl = *(const float2*)&wl2[lid * 2];
    float2 wrv = *(const float2*)&wr2[lid * 2];
    float ps = y0 * wl.x + y1 * wl.y;
    float pr = y0 * wrv.x + y1 * wrv.y;
#pragma unroll
    for (int off = 32; off > 0; off >>= 1) {
        ps += __shfl_down(ps, off, 64);
        pr += __shfl_down(pr, off, 64);
    }
    if (lid == 0) { s_arr[n] = ps; r_arr[n] = pr; }
}

// ---------------- final: scalar mean over edges + sigmoid ----------------
__global__ void k_final2(const float* __restrict__ s_arr, const float* __restrict__ r_arr,
                         const int* __restrict__ rowptr, const int* __restrict__ csr,
                         const float* __restrict__ invd, const float* __restrict__ bl2,
                         float* __restrict__ out, int N) {
    int n = blockIdx.x * blockDim.x + threadIdx.x;
    if (n >= N) return;
    int s = rowptr[n], e = rowptr[n + 1];
    float a = 0.f;
    for (int i = s; i < e; i++) a += s_arr[csr[i]];
    float p = a * invd[n] + r_arr[n] + bl2[0];
    out[n] = 1.f / (1.f + expf(-p));
}

// ---------------- host ----------------
extern "C" void kernel_launch(void* const* d_in, const int* in_sizes, int n_in,
                              void* d_out, int out_size, void* d_ws, size_t ws_size,
                              hipStream_t stream) {
    const float* x   = (const float*)d_in[0];
    const int*   ei  = (const int*)d_in[1];
    const float* wl0 = (const float*)d_in[2];
    const float* bl0 = (const float*)d_in[3];
    const float* wr0 = (const float*)d_in[4];
    const float* g0  = (const float*)d_in[5];
    const float* be0 = (const float*)d_in[6];
    const float* wl1 = (const float*)d_in[7];
    const float* bl1 = (const float*)d_in[8];
    const float* wr1 = (const float*)d_in[9];
    const float* g1  = (const float*)d_in[10];
    const float* be1 = (const float*)d_in[11];
    const float* wl2 = (const float*)d_in[12];
    const float* bl2 = (const float*)d_in[13];
    const float* wr2 = (const float*)d_in[14];
    float* outp = (float*)d_out;

    int N = in_sizes[0] / INDIM;     // 100000
    int E = in_sizes[1] / 2;         // 600000

    char* ws = (char*)d_ws;
    size_t off = 0;
    auto alloc = [&](size_t bytes) { size_t o = off; off = (off + bytes + 255) & ~(size_t)255; return o; };
    int*   degi   = (int*)(ws + alloc((size_t)N * 4));
    int*   cursor = (int*)(ws + alloc((size_t)N * 4));
    int*   rowptr = (int*)(ws + alloc((size_t)(N + 1) * 4));
    int*   csr    = (int*)(ws + alloc((size_t)E * 4));
    float* invd   = (float*)(ws + alloc((size_t)N * 4));
    int*   partial= (int*)(ws + alloc(1024 * 4));
    float* bnbuf  = (float*)(ws + alloc(5120 * 4));
    unsigned short* wcat = (unsigned short*)(ws + alloc(128 * 256 * 2));
    float* sarr   = (float*)(ws + alloc((size_t)N * 4));
    float* rarr   = (float*)(ws + alloc((size_t)N * 4));
    // bnbuf layout: sum0_8[1024] sq0_8[1024] sum1_8[1024] sq1_8[1024] sc0 sh0 sc1 sh1 [128 each]
    float* sum0_8 = bnbuf;
    float* sq0_8  = bnbuf + 1024;
    float* sum1_8 = bnbuf + 2048;
    float* sq1_8  = bnbuf + 3072;
    float* sc0 = bnbuf + 4096, *sh0 = bnbuf + 4224;
    float* sc1 = bnbuf + 4352, *sh1 = bnbuf + 4480;
    float* bufA = (float*)(ws + alloc((size_t)N * HID * 4));            // layer0 raw out
    float* bufB = (float*)(ws + alloc((size_t)N * HID * 4));            // gemm out (raw pre-BN1)
    unsigned short* bufC = (unsigned short*)(ws + alloc((size_t)N * HID * 2)); // bf16 relu(bn0)
    unsigned short* bufD = (unsigned short*)bufA;                       // bf16 agg mean (aliases dead bufA)

    float invN = 1.0f / (float)N;
    int gE = (E + 255) / 256;
    int gN = (N + 255) / 256;
    int gW = (N + 3) / 4;            // wave-per-node kernels
    int gL = (N + 31) / 32;          // layer0 blocks (32 nodes each)
    int gS = (N + 127) / 128;        // gemm blocks
    int nbScan = (N + 1023) / 1024;
    int total8 = N * (HID / 8);

    // zero accumulators (4096 floats of 8-copy BN sums)
    k_zero_i<<<gN, 256, 0, stream>>>(degi, N);
    k_zero_i<<<gN, 256, 0, stream>>>(cursor, N);
    k_zero_i<<<16, 256, 0, stream>>>((int*)bnbuf, 4096);

    // weight prep (independent)
    k_prepw<<<128, 256, 0, stream>>>(wl1, wr1, wcat);

    // CSR build
    k_deg<<<gE, 256, 0, stream>>>(ei + E, degi, E);
    k_scan_partial<<<nbScan, 256, 0, stream>>>(degi, partial, N);
    k_scan_tops<<<1, 1024, 0, stream>>>(partial, nbScan);
    k_scan_write<<<nbScan, 256, 0, stream>>>(degi, partial, rowptr, N, E);
    k_fill<<<gE, 256, 0, stream>>>(ei, cursor, rowptr, csr, E);
    k_invdeg<<<gN, 256, 0, stream>>>(degi, invd, N);

    // layer 0 -> bufA (raw pre-BN) with fused BN0 stats
    k_layer0<<<gL, 256, 0, stream>>>(x, rowptr, csr, invd, wl0, bl0, wr0, bufA,
                                     sum0_8, sq0_8, N);
    k_bnfin8<<<1, 128, 0, stream>>>(sum0_8, sq0_8, g0, be0, sc0, sh0, invN);

    // bf16 relu(bn0(bufA)) -> bufC ; after this bufA is dead (bufD aliases it)
    k_bnapply<<<2048, 256, 0, stream>>>(bufA, sc0, sh0, bufC, total8);

    // layer 1: agg(bufC) -> bufD (bf16) ; MFMA gemm(bufD, bufC) -> bufB with fused BN1 stats
    k_agg_bf<<<gW, 256, 0, stream>>>(bufC, rowptr, csr, invd, bufD, N);
    k_gemm<<<gS, 256, 0, stream>>>(bufD, bufC, wcat, bl1, sum1_8, sq1_8, bufB, N);
    k_bnfin8<<<1, 128, 0, stream>>>(sum1_8, sq1_8, g1, be1, sc1, sh1, invN);

    // layer 2: per-node dots then scalar aggregation + sigmoid
    k_dots<<<gW, 256, 0, stream>>>(bufB, sc1, sh1, wl2, wr2, sarr, rarr, N);
    k_final2<<<gN, 256, 0, stream>>>(sarr, rarr, rowptr, csr, invd, bl2, outp, N);
}

// Round 11
// 246.975 us; speedup vs baseline: 2.8086x; 1.1249x over previous
//
#include <hip/hip_runtime.h>
#include <math.h>

#define HID 128
#define INDIM 6

typedef float4 f4;
typedef __attribute__((ext_vector_type(8))) short short8;
typedef __attribute__((ext_vector_type(4))) float f32x4;

static __device__ inline unsigned short f2bf(float f) {
    union { float f; unsigned int u; } v; v.f = f;
    unsigned int r = v.u + 0x7fffu + ((v.u >> 16) & 1u);   // RNE
    return (unsigned short)(r >> 16);
}
static __device__ inline float bf2f_lo(unsigned int u) {
    union { unsigned int u; float f; } v; v.u = u << 16; return v.f;
}
static __device__ inline float bf2f_hi(unsigned int u) {
    union { unsigned int u; float f; } v; v.u = u & 0xffff0000u; return v.f;
}

// ---------------- utility ----------------
__global__ void k_zero_i(int* p, int n) {
    int i = blockIdx.x * blockDim.x + threadIdx.x;
    if (i < n) p[i] = 0;
}

// ---------------- degree ----------------
__global__ void k_deg(const int* dst, int* deg, int E) {
    int e = blockIdx.x * blockDim.x + threadIdx.x;
    if (e < E) atomicAdd(&deg[dst[e]], 1);
}

// ---------------- hierarchical exclusive scan (deg -> rowptr) ----------------
__global__ void k_scan_partial(const int* __restrict__ deg, int* __restrict__ partial, int N) {
    __shared__ int lds[256];
    int t = threadIdx.x;
    int base = blockIdx.x * 1024 + t * 4;
    int s = 0;
    if (base + 4 <= N) {
        int4 v = *(const int4*)&deg[base];
        s = v.x + v.y + v.z + v.w;
    } else {
        for (int i = 0; i < 4; i++) if (base + i < N) s += deg[base + i];
    }
    lds[t] = s;
    __syncthreads();
    for (int off = 128; off > 0; off >>= 1) {
        if (t < off) lds[t] += lds[t + off];
        __syncthreads();
    }
    if (t == 0) partial[blockIdx.x] = lds[0];
}

__global__ void k_scan_tops(int* partial, int nb) {
    __shared__ int lds[1024];
    int t = threadIdx.x;
    lds[t] = (t < nb) ? partial[t] : 0;
    __syncthreads();
    for (int off = 1; off < 1024; off <<= 1) {
        int v = (t >= off) ? lds[t - off] : 0;
        __syncthreads();
        lds[t] += v;
        __syncthreads();
    }
    if (t < nb) partial[t] = (t == 0) ? 0 : lds[t - 1];
}

__global__ void k_scan_write(const int* __restrict__ deg, const int* __restrict__ partial,
                             int* __restrict__ rowptr, int N, int E) {
    __shared__ int lds[256];
    int t = threadIdx.x;
    int base = blockIdx.x * 1024 + t * 4;
    int v0 = 0, v1 = 0, v2 = 0, v3 = 0;
    if (base + 4 <= N) {
        int4 v = *(const int4*)&deg[base];
        v0 = v.x; v1 = v.y; v2 = v.z; v3 = v.w;
    } else {
        if (base + 0 < N) v0 = deg[base + 0];
        if (base + 1 < N) v1 = deg[base + 1];
        if (base + 2 < N) v2 = deg[base + 2];
        if (base + 3 < N) v3 = deg[base + 3];
    }
    lds[t] = v0 + v1 + v2 + v3;
    __syncthreads();
    for (int off = 1; off < 256; off <<= 1) {
        int v = (t >= off) ? lds[t - off] : 0;
        __syncthreads();
        lds[t] += v;
        __syncthreads();
    }
    int run = partial[blockIdx.x] + ((t == 0) ? 0 : lds[t - 1]);
    if (base + 0 < N) rowptr[base + 0] = run; run += v0;
    if (base + 1 < N) rowptr[base + 1] = run; run += v1;
    if (base + 2 < N) rowptr[base + 2] = run; run += v2;
    if (base + 3 < N) rowptr[base + 3] = run; run += v3;
    if (blockIdx.x == 0 && t == 0) rowptr[N] = E;
}

__global__ void k_fill(const int* ei, int* cursor, const int* rowptr, int* csr, int E) {
    int e = blockIdx.x * blockDim.x + threadIdx.x;
    if (e < E) {
        int d = ei[E + e];
        int pos = rowptr[d] + atomicAdd(&cursor[d], 1);
        csr[pos] = ei[e];
    }
}

__global__ void k_invdeg(const int* deg, float* invd, int N) {
    int i = blockIdx.x * blockDim.x + threadIdx.x;
    if (i < N) invd[i] = 1.0f / (float)max(deg[i], 1);
}

// ---------------- weight prep: concat [Wl1 | Wr1] -> bf16 [128][256] ----------------
__global__ void k_prepw(const float* __restrict__ wl, const float* __restrict__ wr,
                        unsigned short* __restrict__ wcat) {
    int i = blockIdx.x * 256 + threadIdx.x;       // 32768 total
    int o = i >> 8, k = i & 255;
    float v = (k < 128) ? wl[o * 128 + k] : wr[o * 128 + k - 128];
    wcat[i] = f2bf(v);
}

// ---------------- layer 0: agg + 6->128 x2 matmul + fused BN stats ----------------
// 32 nodes/block, 8 threads/node (6 active in gather). LDS-staged padded weights.
__global__ __launch_bounds__(256) void k_layer0(
        const float* __restrict__ x, const int* __restrict__ rowptr,
        const int* __restrict__ csr, const float* __restrict__ invd,
        const float* __restrict__ wl, const float* __restrict__ bl,
        const float* __restrict__ wr, float* __restrict__ out,
        float* __restrict__ sum8, float* __restrict__ sq8, int N) {
    __shared__ float wlds[1600];   // [wl | wr], addr = base + o*6+i + (o>>4)*2  (bank-spread)
    __shared__ float blds[136];    // bias, addr = o + (o>>4)
    __shared__ float mx[32][8];
    __shared__ float xr[32][8];
    __shared__ float ps[4][128];
    __shared__ float pq[4][128];
    int t = threadIdx.x;
    for (int idx = t; idx < 1536; idx += 256) {
        int half = idx >= 768 ? 1 : 0;
        int lin = idx - half * 768;
        int o = lin / 6, i = lin - o * 6;
        float v = half ? wr[lin] : wl[lin];
        wlds[half * 800 + o * 6 + i + (o >> 4) * 2] = v;
    }
    if (t < 128) blds[t + (t >> 4)] = bl[t];
    int nl = t >> 3, f = t & 7;
    int n = blockIdx.x * 32 + nl;
    bool valid = n < N;
    if (f < 6) {
        float mean = 0.f, xv = 0.f;
        if (valid) {
            int s = rowptr[n], e = rowptr[n + 1];
            float acc = 0.f;
            int i = s;
            for (; i + 4 <= e; i += 4) {           // 4-deep MLP unroll
                int i0 = csr[i], i1 = csr[i + 1], i2 = csr[i + 2], i3 = csr[i + 3];
                float a0 = x[i0 * 6 + f], a1 = x[i1 * 6 + f];
                float a2 = x[i2 * 6 + f], a3 = x[i3 * 6 + f];
                acc += (a0 + a1) + (a2 + a3);
            }
            for (; i < e; i++) acc += x[csr[i] * 6 + f];
            mean = acc * invd[n];
            xv = x[n * 6 + f];
        }
        mx[nl][f] = mean;
        xr[nl][f] = xv;
    }
    __syncthreads();
    float m0 = mx[nl][0], m1 = mx[nl][1], m2 = mx[nl][2];
    float m3 = mx[nl][3], m4 = mx[nl][4], m5 = mx[nl][5];
    float r0 = xr[nl][0], r1 = xr[nl][1], r2 = xr[nl][2];
    float r3 = xr[nl][3], r4 = xr[nl][4], r5 = xr[nl][5];
    const float* wA = wlds;
    const float* wB = wlds + 800;
    float sk[16], qk[16];
#pragma unroll
    for (int k4 = 0; k4 < 4; k4++) {
        f4 hv;
        float* hp = &hv.x;
#pragma unroll
        for (int j = 0; j < 4; j++) {
            int k = k4 * 4 + j;
            int o = f * 16 + k;
            int wb = 98 * f + 6 * k;            // o*6 + (o>>4)*2
            float h = blds[o + f];              // o + (o>>4), o>>4 == f
            h += m0 * wA[wb] + m1 * wA[wb + 1] + m2 * wA[wb + 2]
               + m3 * wA[wb + 3] + m4 * wA[wb + 4] + m5 * wA[wb + 5];
            h += r0 * wB[wb] + r1 * wB[wb + 1] + r2 * wB[wb + 2]
               + r3 * wB[wb + 3] + r4 * wB[wb + 4] + r5 * wB[wb + 5];
            hp[j] = h;
            float hs = valid ? h : 0.f;
            sk[k] = hs;
            qk[k] = hs * hs;
        }
        if (valid) *(f4*)&out[(size_t)n * HID + f * 16 + k4 * 4] = hv;
    }
    // stats: reduce over the wave's 8 nodes (lane bits 3..5), then LDS, then 8-copy atomics
    int wv = t >> 6, lane = t & 63;
#pragma unroll
    for (int k = 0; k < 16; k++) {
        float s = sk[k], q = qk[k];
        s += __shfl_xor(s, 8, 64);  q += __shfl_xor(q, 8, 64);
        s += __shfl_xor(s, 16, 64); q += __shfl_xor(q, 16, 64);
        s += __shfl_xor(s, 32, 64); q += __shfl_xor(q, 32, 64);
        if (lane < 8) { ps[wv][lane * 16 + k] = s; pq[wv][lane * 16 + k] = q; }
    }
    __syncthreads();
    if (t < 128) {
        float S = ps[0][t] + ps[1][t] + ps[2][t] + ps[3][t];
        float Q = pq[0][t] + pq[1][t] + pq[2][t] + pq[3][t];
        int slot = (blockIdx.x & 7) * 128 + t;
        atomicAdd(&sum8[slot], S);
        atomicAdd(&sq8[slot], Q);
    }
}

// ---------------- BN finalize from 8-copy accumulators ----------------
__global__ void k_bnfin8(const float* sum8, const float* sq8, const float* g, const float* b,
                         float* scale, float* shift, float invN) {
    int t = threadIdx.x;
    float s = 0.f, q = 0.f;
    for (int c = 0; c < 8; c++) { s += sum8[c * 128 + t]; q += sq8[c * 128 + t]; }
    float mu  = s * invN;
    float var = q * invN - mu * mu;
    float sc  = g[t] * rsqrtf(var + 1e-5f);
    scale[t] = sc;
    shift[t] = b[t] - mu * sc;
}

// ---------------- apply BN+ReLU, emit bf16 rows ----------------
__global__ void k_bnapply(const float* __restrict__ h, const float* __restrict__ scale,
                          const float* __restrict__ shift, unsigned short* __restrict__ out,
                          int total8) {
    int i = blockIdx.x * blockDim.x + threadIdx.x;
    int stride = gridDim.x * blockDim.x;
    for (; i < total8; i += stride) {
        int f8 = (i & 15) * 8;
        f4 v0 = ((const f4*)h)[i * 2];
        f4 v1 = ((const f4*)h)[i * 2 + 1];
        f4 sc0v = *(const f4*)&scale[f8];
        f4 sc1v = *(const f4*)&scale[f8 + 4];
        f4 sh0v = *(const f4*)&shift[f8];
        f4 sh1v = *(const f4*)&shift[f8 + 4];
        unsigned short pk[8];
        pk[0] = f2bf(fmaxf(0.f, fmaf(v0.x, sc0v.x, sh0v.x)));
        pk[1] = f2bf(fmaxf(0.f, fmaf(v0.y, sc0v.y, sh0v.y)));
        pk[2] = f2bf(fmaxf(0.f, fmaf(v0.z, sc0v.z, sh0v.z)));
        pk[3] = f2bf(fmaxf(0.f, fmaf(v0.w, sc0v.w, sh0v.w)));
        pk[4] = f2bf(fmaxf(0.f, fmaf(v1.x, sc1v.x, sh1v.x)));
        pk[5] = f2bf(fmaxf(0.f, fmaf(v1.y, sc1v.y, sh1v.y)));
        pk[6] = f2bf(fmaxf(0.f, fmaf(v1.z, sc1v.z, sh1v.z)));
        pk[7] = f2bf(fmaxf(0.f, fmaf(v1.w, sc1v.w, sh1v.w)));
        *(uint4*)&out[(size_t)i * 8] = *(const uint4*)pk;
    }
}

// ---------------- bf16 mean aggregation (CSR gather, wave per node, 4-deep MLP) ---------
__global__ void k_agg_bf(const unsigned short* __restrict__ hb, const int* __restrict__ rowptr,
                         const int* __restrict__ csr, const float* __restrict__ invd,
                         unsigned short* __restrict__ out, int N) {
    int w = threadIdx.x >> 6, lid = threadIdx.x & 63;
    int n = blockIdx.x * 4 + w;
    if (n >= N) return;
    int s = rowptr[n], e = rowptr[n + 1];
    const unsigned int* hb32 = (const unsigned int*)hb;
    float ax = 0.f, ay = 0.f;
    int i = s;
    for (; i + 4 <= e; i += 4) {                  // issue 4 independent gathers
        int i0 = csr[i], i1 = csr[i + 1], i2 = csr[i + 2], i3 = csr[i + 3];
        unsigned int u0 = hb32[(size_t)i0 * 64 + lid];
        unsigned int u1 = hb32[(size_t)i1 * 64 + lid];
        unsigned int u2 = hb32[(size_t)i2 * 64 + lid];
        unsigned int u3 = hb32[(size_t)i3 * 64 + lid];
        ax += (bf2f_lo(u0) + bf2f_lo(u1)) + (bf2f_lo(u2) + bf2f_lo(u3));
        ay += (bf2f_hi(u0) + bf2f_hi(u1)) + (bf2f_hi(u2) + bf2f_hi(u3));
    }
    for (; i < e; i++) {
        unsigned int u = hb32[(size_t)csr[i] * 64 + lid];
        ax += bf2f_lo(u);
        ay += bf2f_hi(u);
    }
    float id = invd[n];
    unsigned int r = (unsigned int)f2bf(ax * id) | ((unsigned int)f2bf(ay * id) << 16);
    ((unsigned int*)out)[(size_t)n * 64 + lid] = r;
}

// ---------------- MFMA double GEMM + fused BN1 stats ----------------
// block: 128 rows x 128 cols, 4 waves (2x2 of 64x64), K = 256 (chunks of 32)
__global__ __launch_bounds__(256) void k_gemm(
        const unsigned short* __restrict__ Bm, const unsigned short* __restrict__ Ar,
        const unsigned short* __restrict__ wcat, const float* __restrict__ bias,
        float* __restrict__ sum8, float* __restrict__ sq8,
        float* __restrict__ C, int N) {
    __shared__ __align__(16) unsigned short As[128][40];   // 32 k + 8 pad
    __shared__ __align__(16) unsigned short Ws[128][40];
    __shared__ float lds_s[2][128];
    __shared__ float lds_q[2][128];
    int t = threadIdx.x;
    int wave = t >> 6, lane = t & 63;
    int wr = wave >> 1, wc = wave & 1;
    int row0 = blockIdx.x * 128;
    int r = t >> 1, half = t & 1;          // staging: row r, 16-col half

    f32x4 acc[4][4];
#pragma unroll
    for (int m = 0; m < 4; m++)
#pragma unroll
        for (int n = 0; n < 4; n++) acc[m][n] = (f32x4)(0.f);

    for (int chunk = 0; chunk < 8; chunk++) {
        int kb = chunk * 32;
        // ---- stage A (bf16 copy) ----
        int srow = row0 + r;
        int c0 = (chunk & 3) * 32 + half * 16;
        const unsigned short* src = (chunk < 4) ? Bm : Ar;
        if (srow < N) {
            const unsigned short* p = src + (size_t)srow * HID + c0;
            *(uint4*)&As[r][half * 16]     = *(const uint4*)(p);
            *(uint4*)&As[r][half * 16 + 8] = *(const uint4*)(p + 8);
        } else {
            uint4 z = make_uint4(0, 0, 0, 0);
            *(uint4*)&As[r][half * 16]     = z;
            *(uint4*)&As[r][half * 16 + 8] = z;
        }
        // ---- stage W (bf16, L2-resident) ----
        const unsigned short* wp = wcat + r * 256 + kb + half * 16;
        *(uint4*)&Ws[r][half * 16]     = *(const uint4*)(wp + 0);
        *(uint4*)&Ws[r][half * 16 + 8] = *(const uint4*)(wp + 8);
        __syncthreads();

        // ---- MFMA ----
        int lrow = lane & 15, koff = (lane >> 4) * 8;
        short8 af[4], bfr[4];
#pragma unroll
        for (int m = 0; m < 4; m++)
            af[m] = *(const short8*)&As[wr * 64 + m * 16 + lrow][koff];
#pragma unroll
        for (int n = 0; n < 4; n++)
            bfr[n] = *(const short8*)&Ws[wc * 64 + n * 16 + lrow][koff];
#pragma unroll
        for (int m = 0; m < 4; m++)
#pragma unroll
            for (int n = 0; n < 4; n++)
                acc[m][n] = __builtin_amdgcn_mfma_f32_16x16x32_bf16(af[m], bfr[n], acc[m][n], 0, 0, 0);
        __syncthreads();
    }

    // ---- epilogue: store + per-col stats. D: col = lane&15, row = (lane>>4)*4 + reg ----
    int cl = lane & 15, rq = (lane >> 4) * 4;
    float cs[4], cq[4];
#pragma unroll
    for (int n = 0; n < 4; n++) {
        int col = wc * 64 + n * 16 + cl;
        float bn = bias[col];
        float s = 0.f, q = 0.f;
#pragma unroll
        for (int m = 0; m < 4; m++) {
#pragma unroll
            for (int reg = 0; reg < 4; reg++) {
                int row = row0 + wr * 64 + m * 16 + rq + reg;
                float v = acc[m][n][reg] + bn;
                if (row < N) {
                    C[(size_t)row * HID + col] = v;
                    s += v;
                    q += v * v;
                }
            }
        }
        cs[n] = s; cq[n] = q;
    }
#pragma unroll
    for (int n = 0; n < 4; n++) {
        float s = cs[n], q = cq[n];
        s += __shfl_xor(s, 16, 64); q += __shfl_xor(q, 16, 64);
        s += __shfl_xor(s, 32, 64); q += __shfl_xor(q, 32, 64);
        if (lane < 16) {
            int col = wc * 64 + n * 16 + cl;   // cl == lane
            lds_s[wr][col] = s;
            lds_q[wr][col] = q;
        }
    }
    __syncthreads();
    if (t < 128) {
        float S = lds_s[0][t] + lds_s[1][t];
        float Q = lds_q[0][t] + lds_q[1][t];
        int slot = (blockIdx.x & 7) * 128 + t;
        atomicAdd(&sum8[slot], S);
        atomicAdd(&sq8[slot], Q);
    }
}

// ---------------- layer 2 dots: s = relu(bn1(h))·wl2, r = relu(bn1(h))·wr2 ----------------
__global__ void k_dots(const float* __restrict__ h, const float* __restrict__ scale,
                       const float* __restrict__ shift, const float* __restrict__ wl2,
                       const float* __restrict__ wr2, float* __restrict__ s_arr,
                       float* __restrict__ r_arr, int N) {
    int w = threadIdx.x >> 6, lid = threadIdx.x & 63;
    int n = blockIdx.x * 4 + w;
    if (n >= N) return;
    float2 v  = *(const float2*)&h[(size_t)n * HID + lid * 2];
    float2 sc = *(const float2*)&scale[lid * 2];
    float2 sh = *(const float2*)&shift[lid * 2];
    float y0 = fmaxf(0.f, fmaf(v.x, sc.x, sh.x));
    float y1 = fmaxf(0.f, fmaf(v.y, sc.y, sh.y));
    float2 wl = *(const float2*)&wl2[lid * 2];
    float2 wrv = *(const float2*)&wr2[lid * 2];
    float ps = y0 * wl.x + y1 * wl.y;
    float pr = y0 * wrv.x + y1 * wrv.y;
#pragma unroll
    for (int off = 32; off > 0; off >>= 1) {
        ps += __shfl_down(ps, off, 64);
        pr += __shfl_down(pr, off, 64);
    }
    if (lid == 0) { s_arr[n] = ps; r_arr[n] = pr; }
}

// ---------------- final: scalar mean over edges + sigmoid (4-deep MLP) ----------------
__global__ void k_final2(const float* __restrict__ s_arr, const float* __restrict__ r_arr,
                         const int* __restrict__ rowptr, const int* __restrict__ csr,
                         const float* __restrict__ invd, const float* __restrict__ bl2,
                         float* __restrict__ out, int N) {
    int n = blockIdx.x * blockDim.x + threadIdx.x;
    if (n >= N) return;
    int s = rowptr[n], e = rowptr[n + 1];
    float a = 0.f;
    int i = s;
    for (; i + 4 <= e; i += 4) {
        float a0 = s_arr[csr[i]],     a1 = s_arr[csr[i + 1]];
        float a2 = s_arr[csr[i + 2]], a3 = s_arr[csr[i + 3]];
        a += (a0 + a1) + (a2 + a3);
    }
    for (; i < e; i++) a += s_arr[csr[i]];
    float p = a * invd[n] + r_arr[n] + bl2[0];
    out[n] = 1.f / (1.f + expf(-p));
}

// ---------------- host ----------------
extern "C" void kernel_launch(void* const* d_in, const int* in_sizes, int n_in,
                              void* d_out, int out_size, void* d_ws, size_t ws_size,
                              hipStream_t stream) {
    const float* x   = (const float*)d_in[0];
    const int*   ei  = (const int*)d_in[1];
    const float* wl0 = (const float*)d_in[2];
    const float* bl0 = (const float*)d_in[3];
    const float* wr0 = (const float*)d_in[4];
    const float* g0  = (const float*)d_in[5];
    const float* be0 = (const float*)d_in[6];
    const float* wl1 = (const float*)d_in[7];
    const float* bl1 = (const float*)d_in[8];
    const float* wr1 = (const float*)d_in[9];
    const float* g1  = (const float*)d_in[10];
    const float* be1 = (const float*)d_in[11];
    const float* wl2 = (const float*)d_in[12];
    const float* bl2 = (const float*)d_in[13];
    const float* wr2 = (const float*)d_in[14];
    float* outp = (float*)d_out;

    int N = in_sizes[0] / INDIM;     // 100000
    int E = in_sizes[1] / 2;         // 600000

    char* ws = (char*)d_ws;
    size_t off = 0;
    auto alloc = [&](size_t bytes) { size_t o = off; off = (off + bytes + 255) & ~(size_t)255; return o; };
    int*   degi   = (int*)(ws + alloc((size_t)N * 4));
    int*   cursor = (int*)(ws + alloc((size_t)N * 4));
    int*   rowptr = (int*)(ws + alloc((size_t)(N + 1) * 4));
    int*   csr    = (int*)(ws + alloc((size_t)E * 4));
    float* invd   = (float*)(ws + alloc((size_t)N * 4));
    int*   partial= (int*)(ws + alloc(1024 * 4));
    float* bnbuf  = (float*)(ws + alloc(5120 * 4));
    unsigned short* wcat = (unsigned short*)(ws + alloc(128 * 256 * 2));
    float* sarr   = (float*)(ws + alloc((size_t)N * 4));
    float* rarr   = (float*)(ws + alloc((size_t)N * 4));
    // bnbuf layout: sum0_8[1024] sq0_8[1024] sum1_8[1024] sq1_8[1024] sc0 sh0 sc1 sh1 [128 each]
    float* sum0_8 = bnbuf;
    float* sq0_8  = bnbuf + 1024;
    float* sum1_8 = bnbuf + 2048;
    float* sq1_8  = bnbuf + 3072;
    float* sc0 = bnbuf + 4096, *sh0 = bnbuf + 4224;
    float* sc1 = bnbuf + 4352, *sh1 = bnbuf + 4480;
    float* bufA = (float*)(ws + alloc((size_t)N * HID * 4));            // layer0 raw out
    float* bufB = (float*)(ws + alloc((size_t)N * HID * 4));            // gemm out (raw pre-BN1)
    unsigned short* bufC = (unsigned short*)(ws + alloc((size_t)N * HID * 2)); // bf16 relu(bn0)
    unsigned short* bufD = (unsigned short*)bufA;                       // bf16 agg mean (aliases dead bufA)

    float invN = 1.0f / (float)N;
    int gE = (E + 255) / 256;
    int gN = (N + 255) / 256;
    int gW = (N + 3) / 4;            // wave-per-node kernels
    int gL = (N + 31) / 32;          // layer0 blocks (32 nodes each)
    int gS = (N + 127) / 128;        // gemm blocks
    int nbScan = (N + 1023) / 1024;
    int total8 = N * (HID / 8);

    // zero accumulators (4096 floats of 8-copy BN sums)
    k_zero_i<<<gN, 256, 0, stream>>>(degi, N);
    k_zero_i<<<gN, 256, 0, stream>>>(cursor, N);
    k_zero_i<<<16, 256, 0, stream>>>((int*)bnbuf, 4096);

    // weight prep (independent)
    k_prepw<<<128, 256, 0, stream>>>(wl1, wr1, wcat);

    // CSR build
    k_deg<<<gE, 256, 0, stream>>>(ei + E, degi, E);
    k_scan_partial<<<nbScan, 256, 0, stream>>>(degi, partial, N);
    k_scan_tops<<<1, 1024, 0, stream>>>(partial, nbScan);
    k_scan_write<<<nbScan, 256, 0, stream>>>(degi, partial, rowptr, N, E);
    k_fill<<<gE, 256, 0, stream>>>(ei, cursor, rowptr, csr, E);
    k_invdeg<<<gN, 256, 0, stream>>>(degi, invd, N);

    // layer 0 -> bufA (raw pre-BN) with fused BN0 stats
    k_layer0<<<gL, 256, 0, stream>>>(x, rowptr, csr, invd, wl0, bl0, wr0, bufA,
                                     sum0_8, sq0_8, N);
    k_bnfin8<<<1, 128, 0, stream>>>(sum0_8, sq0_8, g0, be0, sc0, sh0, invN);

    // bf16 relu(bn0(bufA)) -> bufC ; after this bufA is dead (bufD aliases it)
    k_bnapply<<<2048, 256, 0, stream>>>(bufA, sc0, sh0, bufC, total8);

    // layer 1: agg(bufC) -> bufD (bf16) ; MFMA gemm(bufD, bufC) -> bufB with fused BN1 stats
    k_agg_bf<<<gW, 256, 0, stream>>>(bufC, rowptr, csr, invd, bufD, N);
    k_gemm<<<gS, 256, 0, stream>>>(bufD, bufC, wcat, bl1, sum1_8, sq1_8, bufB, N);
    k_bnfin8<<<1, 128, 0, stream>>>(sum1_8, sq1_8, g1, be1, sc1, sh1, invN);

    // layer 2: per-node dots then scalar aggregation + sigmoid
    k_dots<<<gW, 256, 0, stream>>>(bufB, sc1, sh1, wl2, wr2, sarr, rarr, N);
    k_final2<<<gN, 256, 0, stream>>>(sarr, rarr, rowptr, csr, invd, bl2, outp, N);
}

// Round 12
// 208.577 us; speedup vs baseline: 3.3256x; 1.1841x over previous
//
#include <hip/hip_runtime.h>
#include <math.h>

#define HID 128
#define INDIM 6

typedef float4 f4;
typedef __attribute__((ext_vector_type(8))) short short8;
typedef __attribute__((ext_vector_type(4))) float f32x4;

static __device__ inline unsigned short f2bf(float f) {
    union { float f; unsigned int u; } v; v.f = f;
    unsigned int r = v.u + 0x7fffu + ((v.u >> 16) & 1u);   // RNE
    return (unsigned short)(r >> 16);
}
static __device__ inline float bf2f_lo(unsigned int u) {
    union { unsigned int u; float f; } v; v.u = u << 16; return v.f;
}
static __device__ inline float bf2f_hi(unsigned int u) {
    union { unsigned int u; float f; } v; v.u = u & 0xffff0000u; return v.f;
}

// ---------------- utility: zero degi[N] + bnbuf[4096] in one launch ----------------
__global__ void k_zero2(int* a, int na, int* b, int nb) {
    int i = blockIdx.x * blockDim.x + threadIdx.x;
    if (i < na) a[i] = 0;
    if (i < nb) b[i] = 0;
}

// ---------------- degree + per-edge rank ----------------
__global__ void k_deg(const int* dst, int* deg, int* rank, int E) {
    int e = blockIdx.x * blockDim.x + threadIdx.x;
    if (e < E) rank[e] = atomicAdd(&deg[dst[e]], 1);
}

// ---------------- hierarchical exclusive scan (deg -> rowptr) ----------------
__global__ void k_scan_partial(const int* __restrict__ deg, int* __restrict__ partial, int N) {
    __shared__ int lds[256];
    int t = threadIdx.x;
    int base = blockIdx.x * 1024 + t * 4;
    int s = 0;
    if (base + 4 <= N) {
        int4 v = *(const int4*)&deg[base];
        s = v.x + v.y + v.z + v.w;
    } else {
        for (int i = 0; i < 4; i++) if (base + i < N) s += deg[base + i];
    }
    lds[t] = s;
    __syncthreads();
    for (int off = 128; off > 0; off >>= 1) {
        if (t < off) lds[t] += lds[t + off];
        __syncthreads();
    }
    if (t == 0) partial[blockIdx.x] = lds[0];
}

__global__ void k_scan_tops(int* partial, int nb) {
    __shared__ int lds[1024];
    int t = threadIdx.x;
    lds[t] = (t < nb) ? partial[t] : 0;
    __syncthreads();
    for (int off = 1; off < 1024; off <<= 1) {
        int v = (t >= off) ? lds[t - off] : 0;
        __syncthreads();
        lds[t] += v;
        __syncthreads();
    }
    if (t < nb) partial[t] = (t == 0) ? 0 : lds[t - 1];
}

__global__ void k_scan_write(const int* __restrict__ deg, const int* __restrict__ partial,
                             int* __restrict__ rowptr, int N, int E) {
    __shared__ int lds[256];
    int t = threadIdx.x;
    int base = blockIdx.x * 1024 + t * 4;
    int v0 = 0, v1 = 0, v2 = 0, v3 = 0;
    if (base + 4 <= N) {
        int4 v = *(const int4*)&deg[base];
        v0 = v.x; v1 = v.y; v2 = v.z; v3 = v.w;
    } else {
        if (base + 0 < N) v0 = deg[base + 0];
        if (base + 1 < N) v1 = deg[base + 1];
        if (base + 2 < N) v2 = deg[base + 2];
        if (base + 3 < N) v3 = deg[base + 3];
    }
    lds[t] = v0 + v1 + v2 + v3;
    __syncthreads();
    for (int off = 1; off < 256; off <<= 1) {
        int v = (t >= off) ? lds[t - off] : 0;
        __syncthreads();
        lds[t] += v;
        __syncthreads();
    }
    int run = partial[blockIdx.x] + ((t == 0) ? 0 : lds[t - 1]);
    if (base + 0 < N) rowptr[base + 0] = run; run += v0;
    if (base + 1 < N) rowptr[base + 1] = run; run += v1;
    if (base + 2 < N) rowptr[base + 2] = run; run += v2;
    if (base + 3 < N) rowptr[base + 3] = run; run += v3;
    if (blockIdx.x == 0 && t == 0) rowptr[N] = E;
}

// ---------------- CSR fill, atomic-free (uses rank from k_deg) ----------------
__global__ void k_fill(const int* ei, const int* rank, const int* rowptr, int* csr, int E) {
    int e = blockIdx.x * blockDim.x + threadIdx.x;
    if (e < E) {
        int d = ei[E + e];
        csr[rowptr[d] + rank[e]] = ei[e];
    }
}

__global__ void k_invdeg(const int* deg, float* invd, int N) {
    int i = blockIdx.x * blockDim.x + threadIdx.x;
    if (i < N) invd[i] = 1.0f / (float)max(deg[i], 1);
}

// ---------------- weight prep: concat [Wl1 | Wr1] -> bf16 [128][256] ----------------
__global__ void k_prepw(const float* __restrict__ wl, const float* __restrict__ wr,
                        unsigned short* __restrict__ wcat) {
    int i = blockIdx.x * 256 + threadIdx.x;       // 32768 total
    int o = i >> 8, k = i & 255;
    float v = (k < 128) ? wl[o * 128 + k] : wr[o * 128 + k - 128];
    wcat[i] = f2bf(v);
}

// ---------------- layer 0: agg + 6->128 x2 matmul + fused BN stats ----------------
// 32 nodes/block, 8 threads/node (6 active in gather). LDS-staged padded weights.
__global__ __launch_bounds__(256) void k_layer0(
        const float* __restrict__ x, const int* __restrict__ rowptr,
        const int* __restrict__ csr, const float* __restrict__ invd,
        const float* __restrict__ wl, const float* __restrict__ bl,
        const float* __restrict__ wr, float* __restrict__ out,
        float* __restrict__ sum8, float* __restrict__ sq8, int N) {
    __shared__ float wlds[1600];   // [wl | wr], addr = base + o*6+i + (o>>4)*2  (bank-spread)
    __shared__ float blds[136];    // bias, addr = o + (o>>4)
    __shared__ float mx[32][8];
    __shared__ float xr[32][8];
    __shared__ float ps[4][128];
    __shared__ float pq[4][128];
    int t = threadIdx.x;
    for (int idx = t; idx < 1536; idx += 256) {
        int half = idx >= 768 ? 1 : 0;
        int lin = idx - half * 768;
        int o = lin / 6, i = lin - o * 6;
        float v = half ? wr[lin] : wl[lin];
        wlds[half * 800 + o * 6 + i + (o >> 4) * 2] = v;
    }
    if (t < 128) blds[t + (t >> 4)] = bl[t];
    int nl = t >> 3, f = t & 7;
    int n = blockIdx.x * 32 + nl;
    bool valid = n < N;
    if (f < 6) {
        float mean = 0.f, xv = 0.f;
        if (valid) {
            int s = rowptr[n], e = rowptr[n + 1];
            float acc = 0.f;
            int i = s;
            for (; i + 4 <= e; i += 4) {           // 4-deep MLP unroll
                int i0 = csr[i], i1 = csr[i + 1], i2 = csr[i + 2], i3 = csr[i + 3];
                float a0 = x[i0 * 6 + f], a1 = x[i1 * 6 + f];
                float a2 = x[i2 * 6 + f], a3 = x[i3 * 6 + f];
                acc += (a0 + a1) + (a2 + a3);
            }
            for (; i < e; i++) acc += x[csr[i] * 6 + f];
            mean = acc * invd[n];
            xv = x[n * 6 + f];
        }
        mx[nl][f] = mean;
        xr[nl][f] = xv;
    }
    __syncthreads();
    float m0 = mx[nl][0], m1 = mx[nl][1], m2 = mx[nl][2];
    float m3 = mx[nl][3], m4 = mx[nl][4], m5 = mx[nl][5];
    float r0 = xr[nl][0], r1 = xr[nl][1], r2 = xr[nl][2];
    float r3 = xr[nl][3], r4 = xr[nl][4], r5 = xr[nl][5];
    const float* wA = wlds;
    const float* wB = wlds + 800;
    float sk[16], qk[16];
#pragma unroll
    for (int k4 = 0; k4 < 4; k4++) {
        f4 hv;
        float* hp = &hv.x;
#pragma unroll
        for (int j = 0; j < 4; j++) {
            int k = k4 * 4 + j;
            int o = f * 16 + k;
            int wb = 98 * f + 6 * k;            // o*6 + (o>>4)*2
            float h = blds[o + f];              // o + (o>>4), o>>4 == f
            h += m0 * wA[wb] + m1 * wA[wb + 1] + m2 * wA[wb + 2]
               + m3 * wA[wb + 3] + m4 * wA[wb + 4] + m5 * wA[wb + 5];
            h += r0 * wB[wb] + r1 * wB[wb + 1] + r2 * wB[wb + 2]
               + r3 * wB[wb + 3] + r4 * wB[wb + 4] + r5 * wB[wb + 5];
            hp[j] = h;
            float hs = valid ? h : 0.f;
            sk[k] = hs;
            qk[k] = hs * hs;
        }
        if (valid) *(f4*)&out[(size_t)n * HID + f * 16 + k4 * 4] = hv;
    }
    // stats: reduce over the wave's 8 nodes (lane bits 3..5), then LDS, then 8-copy atomics
    int wv = t >> 6, lane = t & 63;
#pragma unroll
    for (int k = 0; k < 16; k++) {
        float s = sk[k], q = qk[k];
        s += __shfl_xor(s, 8, 64);  q += __shfl_xor(q, 8, 64);
        s += __shfl_xor(s, 16, 64); q += __shfl_xor(q, 16, 64);
        s += __shfl_xor(s, 32, 64); q += __shfl_xor(q, 32, 64);
        if (lane < 8) { ps[wv][lane * 16 + k] = s; pq[wv][lane * 16 + k] = q; }
    }
    __syncthreads();
    if (t < 128) {
        float S = ps[0][t] + ps[1][t] + ps[2][t] + ps[3][t];
        float Q = pq[0][t] + pq[1][t] + pq[2][t] + pq[3][t];
        int slot = (blockIdx.x & 7) * 128 + t;
        atomicAdd(&sum8[slot], S);
        atomicAdd(&sq8[slot], Q);
    }
}

// ---------------- BN finalize from 8-copy accumulators ----------------
__global__ void k_bnfin8(const float* sum8, const float* sq8, const float* g, const float* b,
                         float* scale, float* shift, float invN) {
    int t = threadIdx.x;
    float s = 0.f, q = 0.f;
    for (int c = 0; c < 8; c++) { s += sum8[c * 128 + t]; q += sq8[c * 128 + t]; }
    float mu  = s * invN;
    float var = q * invN - mu * mu;
    float sc  = g[t] * rsqrtf(var + 1e-5f);
    scale[t] = sc;
    shift[t] = b[t] - mu * sc;
}

// ---------------- apply BN+ReLU, emit bf16 rows ----------------
__global__ void k_bnapply(const float* __restrict__ h, const float* __restrict__ scale,
                          const float* __restrict__ shift, unsigned short* __restrict__ out,
                          int total8) {
    int i = blockIdx.x * blockDim.x + threadIdx.x;
    int stride = gridDim.x * blockDim.x;
    for (; i < total8; i += stride) {
        int f8 = (i & 15) * 8;
        f4 v0 = ((const f4*)h)[i * 2];
        f4 v1 = ((const f4*)h)[i * 2 + 1];
        f4 sc0v = *(const f4*)&scale[f8];
        f4 sc1v = *(const f4*)&scale[f8 + 4];
        f4 sh0v = *(const f4*)&shift[f8];
        f4 sh1v = *(const f4*)&shift[f8 + 4];
        unsigned short pk[8];
        pk[0] = f2bf(fmaxf(0.f, fmaf(v0.x, sc0v.x, sh0v.x)));
        pk[1] = f2bf(fmaxf(0.f, fmaf(v0.y, sc0v.y, sh0v.y)));
        pk[2] = f2bf(fmaxf(0.f, fmaf(v0.z, sc0v.z, sh0v.z)));
        pk[3] = f2bf(fmaxf(0.f, fmaf(v0.w, sc0v.w, sh0v.w)));
        pk[4] = f2bf(fmaxf(0.f, fmaf(v1.x, sc1v.x, sh1v.x)));
        pk[5] = f2bf(fmaxf(0.f, fmaf(v1.y, sc1v.y, sh1v.y)));
        pk[6] = f2bf(fmaxf(0.f, fmaf(v1.z, sc1v.z, sh1v.z)));
        pk[7] = f2bf(fmaxf(0.f, fmaf(v1.w, sc1v.w, sh1v.w)));
        *(uint4*)&out[(size_t)i * 8] = *(const uint4*)pk;
    }
}

// ---------------- bf16 mean aggregation: half-wave per node, uint2 lanes, 4-deep MLP ----
__global__ void k_agg_bf(const unsigned short* __restrict__ hb, const int* __restrict__ rowptr,
                         const int* __restrict__ csr, const float* __restrict__ invd,
                         unsigned short* __restrict__ out, int N) {
    int t = threadIdx.x;
    int w = t >> 6, lid = t & 63;
    int half = lid >> 5, l32 = lid & 31;
    int n = blockIdx.x * 8 + w * 2 + half;
    if (n >= N) return;
    int s = rowptr[n], e = rowptr[n + 1];
    const uint2* hb64 = (const uint2*)hb;          // row stride = 32 uint2 (256 B)
    float ax0 = 0.f, ay0 = 0.f, ax1 = 0.f, ay1 = 0.f;
    int i = s;
    for (; i + 4 <= e; i += 4) {                   // 4 rows x 2 nodes/wave in flight
        int i0 = csr[i], i1 = csr[i + 1], i2 = csr[i + 2], i3 = csr[i + 3];
        uint2 u0 = hb64[(size_t)i0 * 32 + l32];
        uint2 u1 = hb64[(size_t)i1 * 32 + l32];
        uint2 u2 = hb64[(size_t)i2 * 32 + l32];
        uint2 u3 = hb64[(size_t)i3 * 32 + l32];
        ax0 += (bf2f_lo(u0.x) + bf2f_lo(u1.x)) + (bf2f_lo(u2.x) + bf2f_lo(u3.x));
        ay0 += (bf2f_hi(u0.x) + bf2f_hi(u1.x)) + (bf2f_hi(u2.x) + bf2f_hi(u3.x));
        ax1 += (bf2f_lo(u0.y) + bf2f_lo(u1.y)) + (bf2f_lo(u2.y) + bf2f_lo(u3.y));
        ay1 += (bf2f_hi(u0.y) + bf2f_hi(u1.y)) + (bf2f_hi(u2.y) + bf2f_hi(u3.y));
    }
    for (; i < e; i++) {
        uint2 u = hb64[(size_t)csr[i] * 32 + l32];
        ax0 += bf2f_lo(u.x); ay0 += bf2f_hi(u.x);
        ax1 += bf2f_lo(u.y); ay1 += bf2f_hi(u.y);
    }
    float id = invd[n];
    uint2 r;
    r.x = (unsigned int)f2bf(ax0 * id) | ((unsigned int)f2bf(ay0 * id) << 16);
    r.y = (unsigned int)f2bf(ax1 * id) | ((unsigned int)f2bf(ay1 * id) << 16);
    ((uint2*)out)[(size_t)n * 32 + l32] = r;
}

// ---------------- MFMA double GEMM + fused BN1 stats ----------------
// block: 128 rows x 128 cols, 4 waves (2x2 of 64x64), K = 256 (chunks of 32)
__global__ __launch_bounds__(256) void k_gemm(
        const unsigned short* __restrict__ Bm, const unsigned short* __restrict__ Ar,
        const unsigned short* __restrict__ wcat, const float* __restrict__ bias,
        float* __restrict__ sum8, float* __restrict__ sq8,
        float* __restrict__ C, int N) {
    __shared__ __align__(16) unsigned short As[128][40];   // 32 k + 8 pad
    __shared__ __align__(16) unsigned short Ws[128][40];
    __shared__ float lds_s[2][128];
    __shared__ float lds_q[2][128];
    int t = threadIdx.x;
    int wave = t >> 6, lane = t & 63;
    int wr = wave >> 1, wc = wave & 1;
    int row0 = blockIdx.x * 128;
    int r = t >> 1, half = t & 1;          // staging: row r, 16-col half

    f32x4 acc[4][4];
#pragma unroll
    for (int m = 0; m < 4; m++)
#pragma unroll
        for (int n = 0; n < 4; n++) acc[m][n] = (f32x4)(0.f);

    for (int chunk = 0; chunk < 8; chunk++) {
        int kb = chunk * 32;
        // ---- stage A (bf16 copy) ----
        int srow = row0 + r;
        int c0 = (chunk & 3) * 32 + half * 16;
        const unsigned short* src = (chunk < 4) ? Bm : Ar;
        if (srow < N) {
            const unsigned short* p = src + (size_t)srow * HID + c0;
            *(uint4*)&As[r][half * 16]     = *(const uint4*)(p);
            *(uint4*)&As[r][half * 16 + 8] = *(const uint4*)(p + 8);
        } else {
            uint4 z = make_uint4(0, 0, 0, 0);
            *(uint4*)&As[r][half * 16]     = z;
            *(uint4*)&As[r][half * 16 + 8] = z;
        }
        // ---- stage W (bf16, L2-resident) ----
        const unsigned short* wp = wcat + r * 256 + kb + half * 16;
        *(uint4*)&Ws[r][half * 16]     = *(const uint4*)(wp + 0);
        *(uint4*)&Ws[r][half * 16 + 8] = *(const uint4*)(wp + 8);
        __syncthreads();

        // ---- MFMA ----
        int lrow = lane & 15, koff = (lane >> 4) * 8;
        short8 af[4], bfr[4];
#pragma unroll
        for (int m = 0; m < 4; m++)
            af[m] = *(const short8*)&As[wr * 64 + m * 16 + lrow][koff];
#pragma unroll
        for (int n = 0; n < 4; n++)
            bfr[n] = *(const short8*)&Ws[wc * 64 + n * 16 + lrow][koff];
#pragma unroll
        for (int m = 0; m < 4; m++)
#pragma unroll
            for (int n = 0; n < 4; n++)
                acc[m][n] = __builtin_amdgcn_mfma_f32_16x16x32_bf16(af[m], bfr[n], acc[m][n], 0, 0, 0);
        __syncthreads();
    }

    // ---- epilogue: store + per-col stats. D: col = lane&15, row = (lane>>4)*4 + reg ----
    int cl = lane & 15, rq = (lane >> 4) * 4;
    float cs[4], cq[4];
#pragma unroll
    for (int n = 0; n < 4; n++) {
        int col = wc * 64 + n * 16 + cl;
        float bn = bias[col];
        float s = 0.f, q = 0.f;
#pragma unroll
        for (int m = 0; m < 4; m++) {
#pragma unroll
            for (int reg = 0; reg < 4; reg++) {
                int row = row0 + wr * 64 + m * 16 + rq + reg;
                float v = acc[m][n][reg] + bn;
                if (row < N) {
                    C[(size_t)row * HID + col] = v;
                    s += v;
                    q += v * v;
                }
            }
        }
        cs[n] = s; cq[n] = q;
    }
#pragma unroll
    for (int n = 0; n < 4; n++) {
        float s = cs[n], q = cq[n];
        s += __shfl_xor(s, 16, 64); q += __shfl_xor(q, 16, 64);
        s += __shfl_xor(s, 32, 64); q += __shfl_xor(q, 32, 64);
        if (lane < 16) {
            int col = wc * 64 + n * 16 + cl;   // cl == lane
            lds_s[wr][col] = s;
            lds_q[wr][col] = q;
        }
    }
    __syncthreads();
    if (t < 128) {
        float S = lds_s[0][t] + lds_s[1][t];
        float Q = lds_q[0][t] + lds_q[1][t];
        int slot = (blockIdx.x & 7) * 128 + t;
        atomicAdd(&sum8[slot], S);
        atomicAdd(&sq8[slot], Q);
    }
}

// ---------------- layer 2 dots: s = relu(bn1(h))·wl2, r = relu(bn1(h))·wr2 ----------------
__global__ void k_dots(const float* __restrict__ h, const float* __restrict__ scale,
                       const float* __restrict__ shift, const float* __restrict__ wl2,
                       const float* __restrict__ wr2, float* __restrict__ s_arr,
                       float* __restrict__ r_arr, int N) {
    int w = threadIdx.x >> 6, lid = threadIdx.x & 63;
    int n = blockIdx.x * 4 + w;
    if (n >= N) return;
    float2 v  = *(const float2*)&h[(size_t)n * HID + lid * 2];
    float2 sc = *(const float2*)&scale[lid * 2];
    float2 sh = *(const float2*)&shift[lid * 2];
    float y0 = fmaxf(0.f, fmaf(v.x, sc.x, sh.x));
    float y1 = fmaxf(0.f, fmaf(v.y, sc.y, sh.y));
    float2 wl = *(const float2*)&wl2[lid * 2];
    float2 wrv = *(const float2*)&wr2[lid * 2];
    float ps = y0 * wl.x + y1 * wl.y;
    float pr = y0 * wrv.x + y1 * wrv.y;
#pragma unroll
    for (int off = 32; off > 0; off >>= 1) {
        ps += __shfl_down(ps, off, 64);
        pr += __shfl_down(pr, off, 64);
    }
    if (lid == 0) { s_arr[n] = ps; r_arr[n] = pr; }
}

// ---------------- final: scalar mean over edges + sigmoid (4-deep MLP) ----------------
__global__ void k_final2(const float* __restrict__ s_arr, const float* __restrict__ r_arr,
                         const int* __restrict__ rowptr, const int* __restrict__ csr,
                         const float* __restrict__ invd, const float* __restrict__ bl2,
                         float* __restrict__ out, int N) {
    int n = blockIdx.x * blockDim.x + threadIdx.x;
    if (n >= N) return;
    int s = rowptr[n], e = rowptr[n + 1];
    float a = 0.f;
    int i = s;
    for (; i + 4 <= e; i += 4) {
        float a0 = s_arr[csr[i]],     a1 = s_arr[csr[i + 1]];
        float a2 = s_arr[csr[i + 2]], a3 = s_arr[csr[i + 3]];
        a += (a0 + a1) + (a2 + a3);
    }
    for (; i < e; i++) a += s_arr[csr[i]];
    float p = a * invd[n] + r_arr[n] + bl2[0];
    out[n] = 1.f / (1.f + expf(-p));
}

// ---------------- host ----------------
extern "C" void kernel_launch(void* const* d_in, const int* in_sizes, int n_in,
                              void* d_out, int out_size, void* d_ws, size_t ws_size,
                              hipStream_t stream) {
    const float* x   = (const float*)d_in[0];
    const int*   ei  = (const int*)d_in[1];
    const float* wl0 = (const float*)d_in[2];
    const float* bl0 = (const float*)d_in[3];
    const float* wr0 = (const float*)d_in[4];
    const float* g0  = (const float*)d_in[5];
    const float* be0 = (const float*)d_in[6];
    const float* wl1 = (const float*)d_in[7];
    const float* bl1 = (const float*)d_in[8];
    const float* wr1 = (const float*)d_in[9];
    const float* g1  = (const float*)d_in[10];
    const float* be1 = (const float*)d_in[11];
    const float* wl2 = (const float*)d_in[12];
    const float* bl2 = (const float*)d_in[13];
    const float* wr2 = (const float*)d_in[14];
    float* outp = (float*)d_out;

    int N = in_sizes[0] / INDIM;     // 100000
    int E = in_sizes[1] / 2;         // 600000

    char* ws = (char*)d_ws;
    size_t off = 0;
    auto alloc = [&](size_t bytes) { size_t o = off; off = (off + bytes + 255) & ~(size_t)255; return o; };
    int*   degi   = (int*)(ws + alloc((size_t)N * 4));
    int*   rank   = (int*)(ws + alloc((size_t)E * 4));
    int*   rowptr = (int*)(ws + alloc((size_t)(N + 1) * 4));
    int*   csr    = (int*)(ws + alloc((size_t)E * 4));
    float* invd   = (float*)(ws + alloc((size_t)N * 4));
    int*   partial= (int*)(ws + alloc(1024 * 4));
    float* bnbuf  = (float*)(ws + alloc(5120 * 4));
    unsigned short* wcat = (unsigned short*)(ws + alloc(128 * 256 * 2));
    float* sarr   = (float*)(ws + alloc((size_t)N * 4));
    float* rarr   = (float*)(ws + alloc((size_t)N * 4));
    // bnbuf layout: sum0_8[1024] sq0_8[1024] sum1_8[1024] sq1_8[1024] sc0 sh0 sc1 sh1 [128 each]
    float* sum0_8 = bnbuf;
    float* sq0_8  = bnbuf + 1024;
    float* sum1_8 = bnbuf + 2048;
    float* sq1_8  = bnbuf + 3072;
    float* sc0 = bnbuf + 4096, *sh0 = bnbuf + 4224;
    float* sc1 = bnbuf + 4352, *sh1 = bnbuf + 4480;
    float* bufA = (float*)(ws + alloc((size_t)N * HID * 4));            // layer0 raw out
    float* bufB = (float*)(ws + alloc((size_t)N * HID * 4));            // gemm out (raw pre-BN1)
    unsigned short* bufC = (unsigned short*)(ws + alloc((size_t)N * HID * 2)); // bf16 relu(bn0)
    unsigned short* bufD = (unsigned short*)bufA;                       // bf16 agg mean (aliases dead bufA)

    float invN = 1.0f / (float)N;
    int gE = (E + 255) / 256;
    int gN = (N + 255) / 256;
    int gW = (N + 3) / 4;            // wave-per-node kernels
    int gA = (N + 7) / 8;            // agg blocks (8 nodes each, half-wave per node)
    int gL = (N + 31) / 32;          // layer0 blocks (32 nodes each)
    int gS = (N + 127) / 128;        // gemm blocks
    int nbScan = (N + 1023) / 1024;
    int total8 = N * (HID / 8);

    // zero degree + BN accumulators in one launch
    k_zero2<<<gN, 256, 0, stream>>>(degi, N, (int*)bnbuf, 4096);

    // weight prep (independent)
    k_prepw<<<128, 256, 0, stream>>>(wl1, wr1, wcat);

    // CSR build (rank-based, atomic-free fill)
    k_deg<<<gE, 256, 0, stream>>>(ei + E, degi, rank, E);
    k_scan_partial<<<nbScan, 256, 0, stream>>>(degi, partial, N);
    k_scan_tops<<<1, 1024, 0, stream>>>(partial, nbScan);
    k_scan_write<<<nbScan, 256, 0, stream>>>(degi, partial, rowptr, N, E);
    k_fill<<<gE, 256, 0, stream>>>(ei, rank, rowptr, csr, E);
    k_invdeg<<<gN, 256, 0, stream>>>(degi, invd, N);

    // layer 0 -> bufA (raw pre-BN) with fused BN0 stats
    k_layer0<<<gL, 256, 0, stream>>>(x, rowptr, csr, invd, wl0, bl0, wr0, bufA,
                                     sum0_8, sq0_8, N);
    k_bnfin8<<<1, 128, 0, stream>>>(sum0_8, sq0_8, g0, be0, sc0, sh0, invN);

    // bf16 relu(bn0(bufA)) -> bufC ; after this bufA is dead (bufD aliases it)
    k_bnapply<<<2048, 256, 0, stream>>>(bufA, sc0, sh0, bufC, total8);

    // layer 1: agg(bufC) -> bufD (bf16) ; MFMA gemm(bufD, bufC) -> bufB with fused BN1 stats
    k_agg_bf<<<gA, 256, 0, stream>>>(bufC, rowptr, csr, invd, bufD, N);
    k_gemm<<<gS, 256, 0, stream>>>(bufD, bufC, wcat, bl1, sum1_8, sq1_8, bufB, N);
    k_bnfin8<<<1, 128, 0, stream>>>(sum1_8, sq1_8, g1, be1, sc1, sh1, invN);

    // layer 2: per-node dots then scalar aggregation + sigmoid
    k_dots<<<gW, 256, 0, stream>>>(bufB, sc1, sh1, wl2, wr2, sarr, rarr, N);
    k_final2<<<gN, 256, 0, stream>>>(sarr, rarr, rowptr, csr, invd, bl2, outp, N);
}